// Round 1
// baseline (1049.424 us; speedup 1.0000x reference)
//
#include <hip/hip_runtime.h>
#include <math.h>

#define WG 256

__device__ __forceinline__ int lower_bound_i(const int* __restrict__ a, int n, int key) {
    int lo = 0, hi = n;
    while (lo < hi) { int mid = (lo + hi) >> 1; if (a[mid] < key) lo = mid + 1; else hi = mid; }
    return lo;
}

// ---- CSR build ------------------------------------------------------------

// degree histogram over dst (self-loops excluded here; +1 added in k_dis)
__global__ void k_deg(const int* __restrict__ dst, int E, int* __restrict__ deg) {
    int e = blockIdx.x * blockDim.x + threadIdx.x;
    if (e < E) atomicAdd(&deg[dst[e]], 1);
}

// dis[n] = (deg[n]+1)^-0.5   (deg includes self-loop => always > 0)
__global__ void k_dis(const int* __restrict__ deg, float* __restrict__ dis, int N) {
    int n = blockIdx.x * blockDim.x + threadIdx.x;
    if (n < N) dis[n] = 1.0f / sqrtf((float)(deg[n] + 1));
}

__global__ void k_scan1(const int* __restrict__ deg, int N,
                        int* __restrict__ excl, int* __restrict__ bsum) {
    __shared__ int sh[WG];
    int t = threadIdx.x, i = blockIdx.x * WG + t;
    int v = (i < N) ? deg[i] : 0;
    sh[t] = v;
    __syncthreads();
    for (int d = 1; d < WG; d <<= 1) {
        int add = (t >= d) ? sh[t - d] : 0;
        __syncthreads();
        sh[t] += add;
        __syncthreads();
    }
    if (i < N) excl[i] = sh[t] - v;
    if (t == WG - 1) bsum[blockIdx.x] = sh[t];
}

__global__ void k_scan2(const int* __restrict__ bsum, int nb, int* __restrict__ boff) {
    __shared__ int sh[512];
    int t = threadIdx.x;
    int v = (t < nb) ? bsum[t] : 0;
    sh[t] = v;
    __syncthreads();
    for (int d = 1; d < 512; d <<= 1) {
        int add = (t >= d) ? sh[t - d] : 0;
        __syncthreads();
        sh[t] += add;
        __syncthreads();
    }
    if (t < nb) boff[t] = sh[t] - v;
}

__global__ void k_scan3(const int* __restrict__ excl, const int* __restrict__ boff,
                        const int* __restrict__ deg, int N,
                        int* __restrict__ offs, int* __restrict__ cursor) {
    int i = blockIdx.x * WG + threadIdx.x;
    if (i < N) {
        int o = excl[i] + boff[blockIdx.x];
        offs[i] = o;
        cursor[i] = o;
        if (i == N - 1) offs[N] = o + deg[i];
    }
}

__global__ void k_place(const int* __restrict__ src, const int* __restrict__ dst, int E,
                        int* __restrict__ cursor, int* __restrict__ srcs) {
    int e = blockIdx.x * blockDim.x + threadIdx.x;
    if (e < E) {
        int p = atomicAdd(&cursor[dst[e]], 1);
        srcs[p] = src[e];
    }
}

// ---- Layer kernels --------------------------------------------------------

// layer0 transform, pre-scaled by dis: h'[n][f] = (x0[n] @ W0)[f] * dis[n]
__global__ void k_l0(const float* __restrict__ an, const float* __restrict__ pos,
                     const float* __restrict__ W0, const float* __restrict__ dis,
                     float* __restrict__ h, int N) {
    int idx = blockIdx.x * blockDim.x + threadIdx.x;
    int n = idx >> 5, fq = idx & 31;
    if (n >= N) return;
    float a = an[n];
    float px = pos[n * 3 + 0], py = pos[n * 3 + 1], pz = pos[n * 3 + 2];
    float dn = dis[n];
    const float4 w0 = *(const float4*)&W0[0 * 128 + 4 * fq];
    const float4 w1 = *(const float4*)&W0[1 * 128 + 4 * fq];
    const float4 w2 = *(const float4*)&W0[2 * 128 + 4 * fq];
    const float4 w3 = *(const float4*)&W0[3 * 128 + 4 * fq];
    float4 r;
    r.x = (a * w0.x + px * w1.x + py * w2.x + pz * w3.x) * dn;
    r.y = (a * w0.y + px * w1.y + py * w2.y + pz * w3.y) * dn;
    r.z = (a * w0.z + px * w1.z + py * w2.z + pz * w3.z) * dn;
    r.w = (a * w0.w + px * w1.w + py * w2.w + pz * w3.w) * dn;
    *(float4*)&h[(size_t)n * 128 + 4 * fq] = r;
}

// h'[n][f] = (relu(x[n]) @ W)[f] * dis[n]   for 128x128 W
// block = 256 threads; tile = 64 nodes x 128 feats; thread = 8 nodes x 4 feats
__global__ __launch_bounds__(256) void k_gemm(const float* __restrict__ x,
                                              const float* __restrict__ W,
                                              const float* __restrict__ dis,
                                              float* __restrict__ h, int N) {
    int fq = threadIdx.x & 31;
    int ng = threadIdx.x >> 5;
    int n0 = blockIdx.x * 64 + ng * 8;
    float acc[8][4];
#pragma unroll
    for (int i = 0; i < 8; i++)
#pragma unroll
        for (int c = 0; c < 4; c++) acc[i][c] = 0.f;
    int rows[8];
#pragma unroll
    for (int i = 0; i < 8; i++) { int n = n0 + i; rows[i] = min(n, N - 1) * 128; }

    for (int kk = 0; kk < 128; kk += 4) {
        float4 w[4];
#pragma unroll
        for (int j = 0; j < 4; j++) w[j] = *(const float4*)&W[(kk + j) * 128 + 4 * fq];
#pragma unroll
        for (int i = 0; i < 8; i++) {
            float4 xv = *(const float4*)&x[rows[i] + kk];
            xv.x = fmaxf(xv.x, 0.f); xv.y = fmaxf(xv.y, 0.f);
            xv.z = fmaxf(xv.z, 0.f); xv.w = fmaxf(xv.w, 0.f);
            acc[i][0] += xv.x * w[0].x + xv.y * w[1].x + xv.z * w[2].x + xv.w * w[3].x;
            acc[i][1] += xv.x * w[0].y + xv.y * w[1].y + xv.z * w[2].y + xv.w * w[3].y;
            acc[i][2] += xv.x * w[0].z + xv.y * w[1].z + xv.z * w[2].z + xv.w * w[3].z;
            acc[i][3] += xv.x * w[0].w + xv.y * w[1].w + xv.z * w[2].w + xv.w * w[3].w;
        }
    }
#pragma unroll
    for (int i = 0; i < 8; i++) {
        int n = n0 + i;
        if (n < N) {
            float dn = dis[n];
            float4 r = { acc[i][0] * dn, acc[i][1] * dn, acc[i][2] * dn, acc[i][3] * dn };
            *(float4*)&h[(size_t)n * 128 + 4 * fq] = r;
        }
    }
}

// agg[n] = b + dis[n] * (h'[n] + sum_{e in CSR[n]} h'[src_e])
// block = 256 threads = 8 nodes x 32 feature-quads
__global__ void k_agg(const float* __restrict__ h, const float* __restrict__ bias,
                      const float* __restrict__ dis, const int* __restrict__ offs,
                      const int* __restrict__ srcs, float* __restrict__ agg, int N) {
    int fq = threadIdx.x & 31, ng = threadIdx.x >> 5;
    int n = blockIdx.x * 8 + ng;
    if (n >= N) return;
    float4 acc = *(const float4*)&h[(size_t)n * 128 + 4 * fq];   // self-loop term
    int e0 = offs[n], e1 = offs[n + 1];
    for (int e = e0; e < e1; ++e) {
        int s = srcs[e];
        const float4 hv = *(const float4*)&h[(size_t)s * 128 + 4 * fq];
        acc.x += hv.x; acc.y += hv.y; acc.z += hv.z; acc.w += hv.w;
    }
    float dn = dis[n];
    const float4 bv = *(const float4*)&bias[4 * fq];
    float4 r = { bv.x + dn * acc.x, bv.y + dn * acc.y, bv.z + dn * acc.z, bv.w + dn * acc.w };
    *(float4*)&agg[(size_t)n * 128 + 4 * fq] = r;
}

// ---- Pool + head ----------------------------------------------------------

// grid = 64 graphs x 8 chunks; block = 256 = 2 halves x 128 feats
__global__ void k_pool(const float* __restrict__ x, const int* __restrict__ batch,
                       float* __restrict__ pooled, int N) {
    int g = blockIdx.x >> 3, c = blockIdx.x & 7;
    int start = lower_bound_i(batch, N, g);
    int end   = lower_bound_i(batch, N, g + 1);
    int len = end - start;
    int cb = start + (int)((long)len * c / 8);
    int ce = start + (int)((long)len * (c + 1) / 8);
    int f = threadIdx.x & 127, half = threadIdx.x >> 7;
    float acc = 0.f;
    for (int n = cb + half; n < ce; n += 2) acc += fmaxf(x[(size_t)n * 128 + f], 0.f);
    __shared__ float sh[128];
    if (half == 1) sh[f] = acc;
    __syncthreads();
    if (half == 0) atomicAdd(&pooled[g * 128 + f], acc + sh[f]);
}

// 1 block, 64 threads: per-graph mean, linear head, softmax
__global__ void k_head(const float* __restrict__ pooled, const int* __restrict__ batch,
                       const float* __restrict__ linW, const float* __restrict__ linb,
                       float* __restrict__ out, int N) {
    int g = threadIdx.x;
    if (g >= 64) return;
    int start = lower_bound_i(batch, N, g);
    int end   = lower_bound_i(batch, N, g + 1);
    float cnt = fmaxf((float)(end - start), 1.0f);
    float logits[8];
#pragma unroll
    for (int j = 0; j < 8; j++) logits[j] = linb[j];
    for (int f = 0; f < 128; f++) {
        float p = pooled[g * 128 + f] / cnt;
#pragma unroll
        for (int j = 0; j < 8; j++) logits[j] += p * linW[f * 8 + j];
    }
    float m = logits[0];
#pragma unroll
    for (int j = 1; j < 8; j++) m = fmaxf(m, logits[j]);
    float s = 0.f;
    float e[8];
#pragma unroll
    for (int j = 0; j < 8; j++) { e[j] = expf(logits[j] - m); s += e[j]; }
#pragma unroll
    for (int j = 0; j < 8; j++) out[g * 8 + j] = e[j] / s;
}

// ---- Launch ---------------------------------------------------------------

extern "C" void kernel_launch(void* const* d_in, const int* in_sizes, int n_in,
                              void* d_out, int out_size, void* d_ws, size_t ws_size,
                              hipStream_t stream) {
    const float* an   = (const float*)d_in[0];
    const float* pos  = (const float*)d_in[1];
    const float* W0   = (const float*)d_in[2];
    const float* b0   = (const float*)d_in[3];
    const float* W1   = (const float*)d_in[4];
    const float* b1   = (const float*)d_in[5];
    const float* W2   = (const float*)d_in[6];
    const float* b2   = (const float*)d_in[7];
    const float* linW = (const float*)d_in[8];
    const float* linb = (const float*)d_in[9];
    const int*   ei   = (const int*)d_in[10];
    const int*   batch= (const int*)d_in[11];

    int N = in_sizes[0];
    int E = in_sizes[10] / 2;
    const int* esrc = ei;
    const int* edst = ei + E;

    // workspace carve (d_ws is 256B-aligned device memory); total ~111 MB
    char* p = (char*)d_ws;
    auto carve = [&](size_t bytes) -> void* {
        void* r = (void*)p;
        p += (bytes + 255) & ~(size_t)255;
        return r;
    };
    float* bufA   = (float*)carve((size_t)N * 128 * 4);
    float* bufB   = (float*)carve((size_t)N * 128 * 4);
    float* dis    = (float*)carve((size_t)N * 4);
    int*   deg    = (int*)  carve((size_t)N * 4);
    int*   excl   = (int*)  carve((size_t)N * 4);
    int*   offs   = (int*)  carve((size_t)(N + 1) * 4);
    int*   cursor = (int*)  carve((size_t)N * 4);
    int*   bsum   = (int*)  carve(512 * 4);
    int*   boff   = (int*)  carve(512 * 4);
    int*   srcs   = (int*)  carve((size_t)E * 4);
    float* pooled = (float*)carve(64 * 128 * 4);

    hipMemsetAsync(deg, 0, (size_t)N * 4, stream);
    hipMemsetAsync(pooled, 0, 64 * 128 * 4, stream);

    int gb_e = (E + WG - 1) / WG;
    int gb_n = (N + WG - 1) / WG;

    // CSR build (once; reused by all 3 layers)
    k_deg  <<<gb_e, WG, 0, stream>>>(edst, E, deg);
    k_dis  <<<gb_n, WG, 0, stream>>>(deg, dis, N);
    k_scan1<<<gb_n, WG, 0, stream>>>(deg, N, excl, bsum);
    k_scan2<<<1, 512, 0, stream>>>(bsum, gb_n, boff);
    k_scan3<<<gb_n, WG, 0, stream>>>(excl, boff, deg, N, offs, cursor);
    k_place<<<gb_e, WG, 0, stream>>>(esrc, edst, E, cursor, srcs);

    // layer 0
    k_l0  <<<((size_t)N * 32 + WG - 1) / WG, WG, 0, stream>>>(an, pos, W0, dis, bufA, N);
    k_agg <<<(N + 7) / 8, WG, 0, stream>>>(bufA, b0, dis, offs, srcs, bufB, N);
    // layer 1 (relu fused into gemm loads)
    k_gemm<<<(N + 63) / 64, WG, 0, stream>>>(bufB, W1, dis, bufA, N);
    k_agg <<<(N + 7) / 8, WG, 0, stream>>>(bufA, b1, dis, offs, srcs, bufB, N);
    // layer 2
    k_gemm<<<(N + 63) / 64, WG, 0, stream>>>(bufB, W2, dis, bufA, N);
    k_agg <<<(N + 7) / 8, WG, 0, stream>>>(bufA, b2, dis, offs, srcs, bufB, N);

    // pool (relu fused) + head
    k_pool<<<64 * 8, WG, 0, stream>>>(bufB, batch, pooled, N);
    k_head<<<1, 64, 0, stream>>>(pooled, batch, linW, linb, (float*)d_out, N);
}

// Round 2
// 826.092 us; speedup vs baseline: 1.2703x; 1.2703x over previous
//
#include <hip/hip_runtime.h>
#include <math.h>

#define WG 256

__device__ __forceinline__ int lower_bound_i(const int* __restrict__ a, int n, int key) {
    int lo = 0, hi = n;
    while (lo < hi) { int mid = (lo + hi) >> 1; if (a[mid] < key) lo = mid + 1; else hi = mid; }
    return lo;
}

// ---- CSR build ------------------------------------------------------------

__global__ void k_deg(const int* __restrict__ dst, int E, int* __restrict__ deg) {
    int e = blockIdx.x * blockDim.x + threadIdx.x;
    if (e < E) atomicAdd(&deg[dst[e]], 1);
}

__global__ void k_dis(const int* __restrict__ deg, float* __restrict__ dis, int N) {
    int n = blockIdx.x * blockDim.x + threadIdx.x;
    if (n < N) dis[n] = 1.0f / sqrtf((float)(deg[n] + 1));
}

__global__ void k_scan1(const int* __restrict__ deg, int N,
                        int* __restrict__ excl, int* __restrict__ bsum) {
    __shared__ int sh[WG];
    int t = threadIdx.x, i = blockIdx.x * WG + t;
    int v = (i < N) ? deg[i] : 0;
    sh[t] = v;
    __syncthreads();
    for (int d = 1; d < WG; d <<= 1) {
        int add = (t >= d) ? sh[t - d] : 0;
        __syncthreads();
        sh[t] += add;
        __syncthreads();
    }
    if (i < N) excl[i] = sh[t] - v;
    if (t == WG - 1) bsum[blockIdx.x] = sh[t];
}

__global__ void k_scan2(const int* __restrict__ bsum, int nb, int* __restrict__ boff) {
    __shared__ int sh[512];
    int t = threadIdx.x;
    int v = (t < nb) ? bsum[t] : 0;
    sh[t] = v;
    __syncthreads();
    for (int d = 1; d < 512; d <<= 1) {
        int add = (t >= d) ? sh[t - d] : 0;
        __syncthreads();
        sh[t] += add;
        __syncthreads();
    }
    if (t < nb) boff[t] = sh[t] - v;
}

__global__ void k_scan3(const int* __restrict__ excl, const int* __restrict__ boff,
                        const int* __restrict__ deg, int N,
                        int* __restrict__ offs, int* __restrict__ cursor) {
    int i = blockIdx.x * WG + threadIdx.x;
    if (i < N) {
        int o = excl[i] + boff[blockIdx.x];
        offs[i] = o;
        cursor[i] = o;
        if (i == N - 1) offs[N] = o + deg[i];
    }
}

__global__ void k_place(const int* __restrict__ src, const int* __restrict__ dst, int E,
                        int* __restrict__ cursor, int* __restrict__ srcs) {
    int e = blockIdx.x * blockDim.x + threadIdx.x;
    if (e < E) {
        int p = atomicAdd(&cursor[dst[e]], 1);
        srcs[p] = src[e];
    }
}

// ---- Layer kernels --------------------------------------------------------

__global__ void k_l0(const float* __restrict__ an, const float* __restrict__ pos,
                     const float* __restrict__ W0, const float* __restrict__ dis,
                     float* __restrict__ h, int N) {
    int idx = blockIdx.x * blockDim.x + threadIdx.x;
    int n = idx >> 5, fq = idx & 31;
    if (n >= N) return;
    float a = an[n];
    float px = pos[n * 3 + 0], py = pos[n * 3 + 1], pz = pos[n * 3 + 2];
    float dn = dis[n];
    const float4 w0 = *(const float4*)&W0[0 * 128 + 4 * fq];
    const float4 w1 = *(const float4*)&W0[1 * 128 + 4 * fq];
    const float4 w2 = *(const float4*)&W0[2 * 128 + 4 * fq];
    const float4 w3 = *(const float4*)&W0[3 * 128 + 4 * fq];
    float4 r;
    r.x = (a * w0.x + px * w1.x + py * w2.x + pz * w3.x) * dn;
    r.y = (a * w0.y + px * w1.y + py * w2.y + pz * w3.y) * dn;
    r.z = (a * w0.z + px * w1.z + py * w2.z + pz * w3.z) * dn;
    r.w = (a * w0.w + px * w1.w + py * w2.w + pz * w3.w) * dn;
    *(float4*)&h[(size_t)n * 128 + 4 * fq] = r;
}

// h'[n][f] = (relu(x[n]) @ W)[f] * dis[n]   for 128x128 W
// block = 256 threads; tile = 64 nodes x 128 feats, staged in LDS (relu fused).
// thread = 8 nodes x 4 feats; x read from LDS broadcast, W coalesced from L2.
__global__ __launch_bounds__(256) void k_gemm(const float* __restrict__ x,
                                              const float* __restrict__ W,
                                              const float* __restrict__ dis,
                                              float* __restrict__ h, int N) {
    __shared__ float xs[64 * 128];
    int t = threadIdx.x;
    int n0 = blockIdx.x * 64;

    // cooperative coalesced staging: 2048 float4 total, 8 per thread
    const float4* xg = (const float4*)(x + (size_t)n0 * 128);
    float4* xsv = (float4*)xs;
    int valid = min(64, N - n0) * 32;  // valid float4 count in tile
#pragma unroll
    for (int i = 0; i < 8; i++) {
        int idx = t + i * 256;
        float4 v = make_float4(0.f, 0.f, 0.f, 0.f);
        if (idx < valid) v = xg[idx];
        v.x = fmaxf(v.x, 0.f); v.y = fmaxf(v.y, 0.f);
        v.z = fmaxf(v.z, 0.f); v.w = fmaxf(v.w, 0.f);
        xsv[idx] = v;
    }
    __syncthreads();

    int fq = t & 31;
    int ng = t >> 5;
    const float* xrow = &xs[(ng * 8) * 128];

    float acc[8][4];
#pragma unroll
    for (int i = 0; i < 8; i++)
#pragma unroll
        for (int c = 0; c < 4; c++) acc[i][c] = 0.f;

#pragma unroll 2
    for (int kk = 0; kk < 128; kk += 4) {
        float4 w[4];
#pragma unroll
        for (int j = 0; j < 4; j++) w[j] = *(const float4*)&W[(kk + j) * 128 + 4 * fq];
#pragma unroll
        for (int i = 0; i < 8; i++) {
            float4 xv = *(const float4*)&xrow[i * 128 + kk];
            acc[i][0] += xv.x * w[0].x + xv.y * w[1].x + xv.z * w[2].x + xv.w * w[3].x;
            acc[i][1] += xv.x * w[0].y + xv.y * w[1].y + xv.z * w[2].y + xv.w * w[3].y;
            acc[i][2] += xv.x * w[0].z + xv.y * w[1].z + xv.z * w[2].z + xv.w * w[3].z;
            acc[i][3] += xv.x * w[0].w + xv.y * w[1].w + xv.z * w[2].w + xv.w * w[3].w;
        }
    }
#pragma unroll
    for (int i = 0; i < 8; i++) {
        int n = n0 + ng * 8 + i;
        if (n < N) {
            float dn = dis[n];
            float4 r = { acc[i][0] * dn, acc[i][1] * dn, acc[i][2] * dn, acc[i][3] * dn };
            *(float4*)&h[(size_t)n * 128 + 4 * fq] = r;
        }
    }
}

// agg[n] = b + dis[n] * (h'[n] + sum_{e in CSR[n]} h'[src_e])
// block = 256 = 8 nodes x 32 feature-quads; edge loop unrolled x4 for MLP
__global__ void k_agg(const float* __restrict__ h, const float* __restrict__ bias,
                      const float* __restrict__ dis, const int* __restrict__ offs,
                      const int* __restrict__ srcs, float* __restrict__ agg, int N) {
    int fq = threadIdx.x & 31, ng = threadIdx.x >> 5;
    int n = blockIdx.x * 8 + ng;
    if (n >= N) return;
    float4 acc = *(const float4*)&h[(size_t)n * 128 + 4 * fq];   // self-loop term
    int e0 = offs[n], e1 = offs[n + 1];
    int e = e0;
    for (; e + 4 <= e1; e += 4) {
        int s0 = srcs[e + 0], s1 = srcs[e + 1], s2 = srcs[e + 2], s3 = srcs[e + 3];
        float4 h0 = *(const float4*)&h[(size_t)s0 * 128 + 4 * fq];
        float4 h1 = *(const float4*)&h[(size_t)s1 * 128 + 4 * fq];
        float4 h2 = *(const float4*)&h[(size_t)s2 * 128 + 4 * fq];
        float4 h3 = *(const float4*)&h[(size_t)s3 * 128 + 4 * fq];
        acc.x += (h0.x + h1.x) + (h2.x + h3.x);
        acc.y += (h0.y + h1.y) + (h2.y + h3.y);
        acc.z += (h0.z + h1.z) + (h2.z + h3.z);
        acc.w += (h0.w + h1.w) + (h2.w + h3.w);
    }
    for (; e < e1; ++e) {
        int s = srcs[e];
        const float4 hv = *(const float4*)&h[(size_t)s * 128 + 4 * fq];
        acc.x += hv.x; acc.y += hv.y; acc.z += hv.z; acc.w += hv.w;
    }
    float dn = dis[n];
    const float4 bv = *(const float4*)&bias[4 * fq];
    float4 r = { bv.x + dn * acc.x, bv.y + dn * acc.y, bv.z + dn * acc.z, bv.w + dn * acc.w };
    *(float4*)&agg[(size_t)n * 128 + 4 * fq] = r;
}

// ---- Pool + head ----------------------------------------------------------

__global__ void k_pool(const float* __restrict__ x, const int* __restrict__ batch,
                       float* __restrict__ pooled, int N) {
    int g = blockIdx.x >> 3, c = blockIdx.x & 7;
    int start = lower_bound_i(batch, N, g);
    int end   = lower_bound_i(batch, N, g + 1);
    int len = end - start;
    int cb = start + (int)((long)len * c / 8);
    int ce = start + (int)((long)len * (c + 1) / 8);
    int f = threadIdx.x & 127, half = threadIdx.x >> 7;
    float acc = 0.f;
    for (int n = cb + half; n < ce; n += 2) acc += fmaxf(x[(size_t)n * 128 + f], 0.f);
    __shared__ float sh[128];
    if (half == 1) sh[f] = acc;
    __syncthreads();
    if (half == 0) atomicAdd(&pooled[g * 128 + f], acc + sh[f]);
}

__global__ void k_head(const float* __restrict__ pooled, const int* __restrict__ batch,
                       const float* __restrict__ linW, const float* __restrict__ linb,
                       float* __restrict__ out, int N) {
    int g = threadIdx.x;
    if (g >= 64) return;
    int start = lower_bound_i(batch, N, g);
    int end   = lower_bound_i(batch, N, g + 1);
    float cnt = fmaxf((float)(end - start), 1.0f);
    float logits[8];
#pragma unroll
    for (int j = 0; j < 8; j++) logits[j] = linb[j];
    for (int f = 0; f < 128; f++) {
        float p = pooled[g * 128 + f] / cnt;
#pragma unroll
        for (int j = 0; j < 8; j++) logits[j] += p * linW[f * 8 + j];
    }
    float m = logits[0];
#pragma unroll
    for (int j = 1; j < 8; j++) m = fmaxf(m, logits[j]);
    float s = 0.f;
    float e[8];
#pragma unroll
    for (int j = 0; j < 8; j++) { e[j] = expf(logits[j] - m); s += e[j]; }
#pragma unroll
    for (int j = 0; j < 8; j++) out[g * 8 + j] = e[j] / s;
}

// ---- Launch ---------------------------------------------------------------

extern "C" void kernel_launch(void* const* d_in, const int* in_sizes, int n_in,
                              void* d_out, int out_size, void* d_ws, size_t ws_size,
                              hipStream_t stream) {
    const float* an   = (const float*)d_in[0];
    const float* pos  = (const float*)d_in[1];
    const float* W0   = (const float*)d_in[2];
    const float* b0   = (const float*)d_in[3];
    const float* W1   = (const float*)d_in[4];
    const float* b1   = (const float*)d_in[5];
    const float* W2   = (const float*)d_in[6];
    const float* b2   = (const float*)d_in[7];
    const float* linW = (const float*)d_in[8];
    const float* linb = (const float*)d_in[9];
    const int*   ei   = (const int*)d_in[10];
    const int*   batch= (const int*)d_in[11];

    int N = in_sizes[0];
    int E = in_sizes[10] / 2;
    const int* esrc = ei;
    const int* edst = ei + E;

    char* p = (char*)d_ws;
    auto carve = [&](size_t bytes) -> void* {
        void* r = (void*)p;
        p += (bytes + 255) & ~(size_t)255;
        return r;
    };
    float* bufA   = (float*)carve((size_t)N * 128 * 4);
    float* bufB   = (float*)carve((size_t)N * 128 * 4);
    float* dis    = (float*)carve((size_t)N * 4);
    int*   deg    = (int*)  carve((size_t)N * 4);
    int*   excl   = (int*)  carve((size_t)N * 4);
    int*   offs   = (int*)  carve((size_t)(N + 1) * 4);
    int*   cursor = (int*)  carve((size_t)N * 4);
    int*   bsum   = (int*)  carve(512 * 4);
    int*   boff   = (int*)  carve(512 * 4);
    int*   srcs   = (int*)  carve((size_t)E * 4);
    float* pooled = (float*)carve(64 * 128 * 4);

    hipMemsetAsync(deg, 0, (size_t)N * 4, stream);
    hipMemsetAsync(pooled, 0, 64 * 128 * 4, stream);

    int gb_e = (E + WG - 1) / WG;
    int gb_n = (N + WG - 1) / WG;

    k_deg  <<<gb_e, WG, 0, stream>>>(edst, E, deg);
    k_dis  <<<gb_n, WG, 0, stream>>>(deg, dis, N);
    k_scan1<<<gb_n, WG, 0, stream>>>(deg, N, excl, bsum);
    k_scan2<<<1, 512, 0, stream>>>(bsum, gb_n, boff);
    k_scan3<<<gb_n, WG, 0, stream>>>(excl, boff, deg, N, offs, cursor);
    k_place<<<gb_e, WG, 0, stream>>>(esrc, edst, E, cursor, srcs);

    k_l0  <<<((size_t)N * 32 + WG - 1) / WG, WG, 0, stream>>>(an, pos, W0, dis, bufA, N);
    k_agg <<<(N + 7) / 8, WG, 0, stream>>>(bufA, b0, dis, offs, srcs, bufB, N);
    k_gemm<<<(N + 63) / 64, WG, 0, stream>>>(bufB, W1, dis, bufA, N);
    k_agg <<<(N + 7) / 8, WG, 0, stream>>>(bufA, b1, dis, offs, srcs, bufB, N);
    k_gemm<<<(N + 63) / 64, WG, 0, stream>>>(bufB, W2, dis, bufA, N);
    k_agg <<<(N + 7) / 8, WG, 0, stream>>>(bufA, b2, dis, offs, srcs, bufB, N);

    k_pool<<<64 * 8, WG, 0, stream>>>(bufB, batch, pooled, N);
    k_head<<<1, 64, 0, stream>>>(pooled, batch, linW, linb, (float*)d_out, N);
}

// Round 3
// 546.279 us; speedup vs baseline: 1.9210x; 1.5122x over previous
//
#include <hip/hip_runtime.h>
#include <hip/hip_fp16.h>
#include <math.h>

#define WG 256
#define MAXNB 128          // max buckets (node-range 1024 each -> N <= 131072)
#define BSHIFT 10
#define BCAP 24576         // per-bucket pair capacity (E/nb ~16.3K avg)
#define PART_CAP 64
#define PART_FLUSH 32

__device__ __forceinline__ int lower_bound_i(const int* __restrict__ a, int n, int key) {
    int lo = 0, hi = n;
    while (lo < hi) { int mid = (lo + hi) >> 1; if (a[mid] < key) lo = mid + 1; else hi = mid; }
    return lo;
}

// half8 <-> float8 helpers (raw = 16B of 8 halves)
__device__ __forceinline__ void h8_to_f8(const float4 raw, float* f) {
    union { float s; __half2 h; } u;
    u.s = raw.x; float2 a = __half22float2(u.h);
    u.s = raw.y; float2 b = __half22float2(u.h);
    u.s = raw.z; float2 c = __half22float2(u.h);
    u.s = raw.w; float2 d = __half22float2(u.h);
    f[0]=a.x; f[1]=a.y; f[2]=b.x; f[3]=b.y; f[4]=c.x; f[5]=c.y; f[6]=d.x; f[7]=d.y;
}
__device__ __forceinline__ float4 f8_to_h8(const float* f) {
    union { float s; __half2 h; } u;
    float4 r;
    u.h = __floats2half2_rn(f[0], f[1]); r.x = u.s;
    u.h = __floats2half2_rn(f[2], f[3]); r.y = u.s;
    u.h = __floats2half2_rn(f[4], f[5]); r.z = u.s;
    u.h = __floats2half2_rn(f[6], f[7]); r.w = u.s;
    return r;
}
__device__ __forceinline__ float4 h4_to_f4(const float2 raw) {
    union { float s; __half2 h; } u;
    u.s = raw.x; float2 a = __half22float2(u.h);
    u.s = raw.y; float2 b = __half22float2(u.h);
    return make_float4(a.x, a.y, b.x, b.y);
}
__device__ __forceinline__ float2 f4_to_h4(const float4 v) {
    union { float s; __half2 h; } u;
    float2 r;
    u.h = __floats2half2_rn(v.x, v.y); r.x = u.s;
    u.h = __floats2half2_rn(v.z, v.w); r.y = u.s;
    return r;
}

// ---- CSR build: phase 1 — bucket partition with LDS-staged coalesced flush ----
__global__ __launch_bounds__(256) void k_part(const int* __restrict__ esrc,
        const int* __restrict__ edst, int E, int nb,
        int* __restrict__ gcur, int2* __restrict__ pairs) {
    __shared__ int2 buf[MAXNB * PART_CAP];   // 64 KB
    __shared__ int cnt[MAXNB];
    __shared__ int flist[MAXNB];
    __shared__ int fbase[MAXNB];
    __shared__ int fn;
    int t = threadIdx.x;
    if (t < MAXNB) cnt[t] = 0;
    if (t == 0) fn = 0;
    __syncthreads();
    int chunk = (E + gridDim.x - 1) / gridDim.x;
    int e0 = blockIdx.x * chunk, e1 = min(E, e0 + chunk);
    for (int base = e0; base < e1; base += 256) {
        int e = base + t;
        if (e < e1) {
            int d = edst[e], s = esrc[e];
            int b = d >> BSHIFT;
            int pos = atomicAdd(&cnt[b], 1);
            if (pos < PART_CAP) buf[b * PART_CAP + pos] = make_int2(s, d);
            else {
                int g = atomicAdd(&gcur[b], 1);
                if (g < BCAP) pairs[(size_t)b * BCAP + g] = make_int2(s, d);
            }
        }
        __syncthreads();
        if (t < nb && cnt[t] >= PART_FLUSH) { int i = atomicAdd(&fn, 1); flist[i] = t; }
        __syncthreads();
        int nf = fn;
        if (t < nf) { int b = flist[t]; fbase[t] = atomicAdd(&gcur[b], min(cnt[b], PART_CAP)); }
        __syncthreads();
        for (int i = 0; i < nf; i++) {
            int b = flist[i]; int c = min(cnt[b], PART_CAP);
            int p = fbase[i] + t;
            if (t < c && p < BCAP) pairs[(size_t)b * BCAP + p] = buf[b * PART_CAP + t];
        }
        __syncthreads();
        if (t < nf) cnt[flist[t]] = 0;
        if (t == 0) fn = 0;
        __syncthreads();
    }
    // final flush (threshold >= 1)
    if (t < nb && cnt[t] > 0) { int i = atomicAdd(&fn, 1); flist[i] = t; }
    __syncthreads();
    int nf = fn;
    if (t < nf) { int b = flist[t]; fbase[t] = atomicAdd(&gcur[b], min(cnt[b], PART_CAP)); }
    __syncthreads();
    for (int i = 0; i < nf; i++) {
        int b = flist[i]; int c = min(cnt[b], PART_CAP);
        int p = fbase[i] + t;
        if (t < c && p < BCAP) pairs[(size_t)b * BCAP + p] = buf[b * PART_CAP + t];
    }
}

// ---- CSR build: phase 1.5 — bucket-count exclusive scan -----------------------
__global__ void k_bscan(const int* __restrict__ gcur, int nb, int* __restrict__ bstart) {
    __shared__ int sh[128];
    int t = threadIdx.x;
    int v = (t < nb) ? min(gcur[t], BCAP) : 0;
    sh[t] = v;
    __syncthreads();
    for (int d = 1; d < 128; d <<= 1) {
        int a = (t >= d) ? sh[t - d] : 0;
        __syncthreads();
        sh[t] += a;
        __syncthreads();
    }
    if (t < nb) bstart[t] = sh[t] - v;
    if (t == nb - 1) bstart[nb] = sh[t];
}

// ---- CSR build: phase 2 — per-bucket histogram + scan + place (all in LDS) ----
__global__ __launch_bounds__(256) void k_build(const int2* __restrict__ pairs,
        const int* __restrict__ gcur, const int* __restrict__ bstart,
        int N, int* __restrict__ offs, int* __restrict__ srcs, float* __restrict__ dis) {
    __shared__ int cnt[1024];
    __shared__ int wtot[4];
    int b = blockIdx.x, t = threadIdx.x;
    int n0 = b << BSHIFT;
    for (int i = t; i < 1024; i += 256) cnt[i] = 0;
    __syncthreads();
    int m = min(gcur[b], BCAP);
    const int2* pb = &pairs[(size_t)b * BCAP];
    for (int i = t; i < m; i += 256) {
        int2 p = pb[i];
        atomicAdd(&cnt[p.y - n0], 1);
    }
    __syncthreads();
    int v0 = cnt[4 * t], v1 = cnt[4 * t + 1], v2 = cnt[4 * t + 2], v3 = cnt[4 * t + 3];
    int ts = v0 + v1 + v2 + v3;
    int lane = t & 63, wid = t >> 6;
    int x = ts;
    #pragma unroll
    for (int d = 1; d < 64; d <<= 1) { int y = __shfl_up(x, d); if (lane >= d) x += y; }
    if (lane == 63) wtot[wid] = x;
    __syncthreads();
    int woff = 0;
    for (int w = 0; w < wid; w++) woff += wtot[w];
    int excl = woff + x - ts;                // block-exclusive prefix
    int bs = bstart[b];
    int o0 = excl, o1 = excl + v0, o2 = o1 + v1, o3 = o2 + v2;
    cnt[4 * t] = o0; cnt[4 * t + 1] = o1; cnt[4 * t + 2] = o2; cnt[4 * t + 3] = o3;
    int n = n0 + 4 * t;
    if (n + 0 < N) { offs[n + 0] = bs + o0; dis[n + 0] = rsqrtf((float)(v0 + 1)); }
    if (n + 1 < N) { offs[n + 1] = bs + o1; dis[n + 1] = rsqrtf((float)(v1 + 1)); }
    if (n + 2 < N) { offs[n + 2] = bs + o2; dis[n + 2] = rsqrtf((float)(v2 + 1)); }
    if (n + 3 < N) { offs[n + 3] = bs + o3; dis[n + 3] = rsqrtf((float)(v3 + 1)); }
    if (b == gridDim.x - 1 && t == 255) offs[N] = bs + woff + x;  // = E
    __syncthreads();
    for (int i = t; i < m; i += 256) {
        int2 p = pb[i];
        int pos = atomicAdd(&cnt[p.y - n0], 1);
        srcs[bs + pos] = p.x;
    }
}

// ---- Layer kernels --------------------------------------------------------

// layer0: h'[n][f] = (x0[n] @ W0)[f] * dis[n], stored fp16
__global__ void k_l0(const float* __restrict__ an, const float* __restrict__ pos,
                     const float* __restrict__ W0, const float* __restrict__ dis,
                     __half* __restrict__ h, int N) {
    int idx = blockIdx.x * blockDim.x + threadIdx.x;
    int n = idx >> 5, fq = idx & 31;
    if (n >= N) return;
    float a = an[n];
    float px = pos[n * 3 + 0], py = pos[n * 3 + 1], pz = pos[n * 3 + 2];
    float dn = dis[n];
    const float4 w0 = *(const float4*)&W0[0 * 128 + 4 * fq];
    const float4 w1 = *(const float4*)&W0[1 * 128 + 4 * fq];
    const float4 w2 = *(const float4*)&W0[2 * 128 + 4 * fq];
    const float4 w3 = *(const float4*)&W0[3 * 128 + 4 * fq];
    float4 r;
    r.x = (a * w0.x + px * w1.x + py * w2.x + pz * w3.x) * dn;
    r.y = (a * w0.y + px * w1.y + py * w2.y + pz * w3.y) * dn;
    r.z = (a * w0.z + px * w1.z + py * w2.z + pz * w3.z) * dn;
    r.w = (a * w0.w + px * w1.w + py * w2.w + pz * w3.w) * dn;
    *(float2*)&h[(size_t)n * 128 + 4 * fq] = f4_to_h4(r);
}

// h'[n][f] = (relu(x[n]) @ W)[f] * dis[n]; x fp16 staged to fp32 LDS tile
__global__ __launch_bounds__(256) void k_gemm(const __half* __restrict__ x,
                                              const float* __restrict__ W,
                                              const float* __restrict__ dis,
                                              __half* __restrict__ h, int N) {
    __shared__ float xs[64 * 128];
    int t = threadIdx.x;
    int n0 = blockIdx.x * 64;

    const uint2* xg = (const uint2*)(x + (size_t)n0 * 128);  // 4 halves per uint2
    float4* xsv = (float4*)xs;
    int valid = min(64, N - n0) * 32;
#pragma unroll
    for (int i = 0; i < 8; i++) {
        int idx = t + i * 256;
        float4 v = make_float4(0.f, 0.f, 0.f, 0.f);
        if (idx < valid) {
            uint2 raw = xg[idx];
            float2 praw = make_float2(__uint_as_float(raw.x), __uint_as_float(raw.y));
            v = h4_to_f4(praw);
        }
        v.x = fmaxf(v.x, 0.f); v.y = fmaxf(v.y, 0.f);
        v.z = fmaxf(v.z, 0.f); v.w = fmaxf(v.w, 0.f);
        xsv[idx] = v;
    }
    __syncthreads();

    int fq = t & 31;
    int ng = t >> 5;
    const float* xrow = &xs[(ng * 8) * 128];

    float acc[8][4];
#pragma unroll
    for (int i = 0; i < 8; i++)
#pragma unroll
        for (int c = 0; c < 4; c++) acc[i][c] = 0.f;

#pragma unroll 2
    for (int kk = 0; kk < 128; kk += 4) {
        float4 w[4];
#pragma unroll
        for (int j = 0; j < 4; j++) w[j] = *(const float4*)&W[(kk + j) * 128 + 4 * fq];
#pragma unroll
        for (int i = 0; i < 8; i++) {
            float4 xv = *(const float4*)&xrow[i * 128 + kk];
            acc[i][0] += xv.x * w[0].x + xv.y * w[1].x + xv.z * w[2].x + xv.w * w[3].x;
            acc[i][1] += xv.x * w[0].y + xv.y * w[1].y + xv.z * w[2].y + xv.w * w[3].y;
            acc[i][2] += xv.x * w[0].z + xv.y * w[1].z + xv.z * w[2].z + xv.w * w[3].z;
            acc[i][3] += xv.x * w[0].w + xv.y * w[1].w + xv.z * w[2].w + xv.w * w[3].w;
        }
    }
#pragma unroll
    for (int i = 0; i < 8; i++) {
        int n = n0 + ng * 8 + i;
        if (n < N) {
            float dn = dis[n];
            float4 r = { acc[i][0] * dn, acc[i][1] * dn, acc[i][2] * dn, acc[i][3] * dn };
            *(float2*)&h[(size_t)n * 128 + 4 * fq] = f4_to_h4(r);
        }
    }
}

// agg[n] = b + dis[n] * (h'[n] + sum_src h'[src]); fp16 rows, fp32 accum
// block = 256 = 16 nodes x 16 lanes; lane handles 8 feats (16B loads)
__global__ __launch_bounds__(256) void k_agg(const __half* __restrict__ h,
                      const float* __restrict__ bias,
                      const float* __restrict__ dis, const int* __restrict__ offs,
                      const int* __restrict__ srcs, __half* __restrict__ agg, int N) {
    int fq = threadIdx.x & 15, ng = threadIdx.x >> 4;
    int n = blockIdx.x * 16 + ng;
    if (n >= N) return;
    float acc[8], tmp[8];
    {
        float4 raw = *(const float4*)&h[(size_t)n * 128 + 8 * fq];  // self-loop term
        h8_to_f8(raw, acc);
    }
    int e0 = offs[n], e1 = offs[n + 1];
    int e = e0;
    for (; e + 4 <= e1; e += 4) {
        int s0 = srcs[e + 0], s1 = srcs[e + 1], s2 = srcs[e + 2], s3 = srcs[e + 3];
        float4 r0 = *(const float4*)&h[(size_t)s0 * 128 + 8 * fq];
        float4 r1 = *(const float4*)&h[(size_t)s1 * 128 + 8 * fq];
        float4 r2 = *(const float4*)&h[(size_t)s2 * 128 + 8 * fq];
        float4 r3 = *(const float4*)&h[(size_t)s3 * 128 + 8 * fq];
        h8_to_f8(r0, tmp);
#pragma unroll
        for (int k = 0; k < 8; k++) acc[k] += tmp[k];
        h8_to_f8(r1, tmp);
#pragma unroll
        for (int k = 0; k < 8; k++) acc[k] += tmp[k];
        h8_to_f8(r2, tmp);
#pragma unroll
        for (int k = 0; k < 8; k++) acc[k] += tmp[k];
        h8_to_f8(r3, tmp);
#pragma unroll
        for (int k = 0; k < 8; k++) acc[k] += tmp[k];
    }
    for (; e < e1; ++e) {
        int s = srcs[e];
        float4 r0 = *(const float4*)&h[(size_t)s * 128 + 8 * fq];
        h8_to_f8(r0, tmp);
#pragma unroll
        for (int k = 0; k < 8; k++) acc[k] += tmp[k];
    }
    float dn = dis[n];
    const float4 bv0 = *(const float4*)&bias[8 * fq];
    const float4 bv1 = *(const float4*)&bias[8 * fq + 4];
    float outv[8];
    outv[0] = bv0.x + dn * acc[0]; outv[1] = bv0.y + dn * acc[1];
    outv[2] = bv0.z + dn * acc[2]; outv[3] = bv0.w + dn * acc[3];
    outv[4] = bv1.x + dn * acc[4]; outv[5] = bv1.y + dn * acc[5];
    outv[6] = bv1.z + dn * acc[6]; outv[7] = bv1.w + dn * acc[7];
    *(float4*)&agg[(size_t)n * 128 + 8 * fq] = f8_to_h8(outv);
}

// ---- Pool + head ----------------------------------------------------------

__global__ void k_pool(const __half* __restrict__ x, const int* __restrict__ batch,
                       float* __restrict__ pooled, int N) {
    int g = blockIdx.x >> 3, c = blockIdx.x & 7;
    int start = lower_bound_i(batch, N, g);
    int end   = lower_bound_i(batch, N, g + 1);
    int len = end - start;
    int cb = start + (int)((long)len * c / 8);
    int ce = start + (int)((long)len * (c + 1) / 8);
    int f = threadIdx.x & 127, half = threadIdx.x >> 7;
    float acc = 0.f;
    for (int n = cb + half; n < ce; n += 2) acc += fmaxf(__half2float(x[(size_t)n * 128 + f]), 0.f);
    __shared__ float sh[128];
    if (half == 1) sh[f] = acc;
    __syncthreads();
    if (half == 0) atomicAdd(&pooled[g * 128 + f], acc + sh[f]);
}

__global__ void k_head(const float* __restrict__ pooled, const int* __restrict__ batch,
                       const float* __restrict__ linW, const float* __restrict__ linb,
                       float* __restrict__ out, int N) {
    int g = threadIdx.x;
    if (g >= 64) return;
    int start = lower_bound_i(batch, N, g);
    int end   = lower_bound_i(batch, N, g + 1);
    float cnt = fmaxf((float)(end - start), 1.0f);
    float logits[8];
#pragma unroll
    for (int j = 0; j < 8; j++) logits[j] = linb[j];
    for (int f = 0; f < 128; f++) {
        float p = pooled[g * 128 + f] / cnt;
#pragma unroll
        for (int j = 0; j < 8; j++) logits[j] += p * linW[f * 8 + j];
    }
    float m = logits[0];
#pragma unroll
    for (int j = 1; j < 8; j++) m = fmaxf(m, logits[j]);
    float s = 0.f;
    float e[8];
#pragma unroll
    for (int j = 0; j < 8; j++) { e[j] = expf(logits[j] - m); s += e[j]; }
#pragma unroll
    for (int j = 0; j < 8; j++) out[g * 8 + j] = e[j] / s;
}

// ---- Launch ---------------------------------------------------------------

extern "C" void kernel_launch(void* const* d_in, const int* in_sizes, int n_in,
                              void* d_out, int out_size, void* d_ws, size_t ws_size,
                              hipStream_t stream) {
    const float* an   = (const float*)d_in[0];
    const float* pos  = (const float*)d_in[1];
    const float* W0   = (const float*)d_in[2];
    const float* b0   = (const float*)d_in[3];
    const float* W1   = (const float*)d_in[4];
    const float* b1   = (const float*)d_in[5];
    const float* W2   = (const float*)d_in[6];
    const float* b2   = (const float*)d_in[7];
    const float* linW = (const float*)d_in[8];
    const float* linb = (const float*)d_in[9];
    const int*   ei   = (const int*)d_in[10];
    const int*   batch= (const int*)d_in[11];

    int N = in_sizes[0];
    int E = in_sizes[10] / 2;
    const int* esrc = ei;
    const int* edst = ei + E;
    int nb = (N + (1 << BSHIFT) - 1) >> BSHIFT;   // 98 for N=100000

    char* p = (char*)d_ws;
    auto carve = [&](size_t bytes) -> void* {
        void* r = (void*)p;
        p += (bytes + 255) & ~(size_t)255;
        return r;
    };
    __half* bufA  = (__half*)carve((size_t)N * 128 * 2);
    __half* bufB  = (__half*)carve((size_t)N * 128 * 2);
    float* dis    = (float*)carve((size_t)N * 4);
    int*   offs   = (int*)  carve((size_t)(N + 1) * 4);
    int*   srcs   = (int*)  carve((size_t)E * 4);
    int2*  pairs  = (int2*) carve((size_t)MAXNB * BCAP * 8);
    int*   gcur   = (int*)  carve(MAXNB * 4);
    int*   bstart = (int*)  carve((MAXNB + 1) * 4);
    float* pooled = (float*)carve(64 * 128 * 4);

    hipMemsetAsync(gcur, 0, MAXNB * 4, stream);
    hipMemsetAsync(pooled, 0, 64 * 128 * 4, stream);

    // CSR build
    k_part <<<512, WG, 0, stream>>>(esrc, edst, E, nb, gcur, pairs);
    k_bscan<<<1, 128, 0, stream>>>(gcur, nb, bstart);
    k_build<<<nb, WG, 0, stream>>>(pairs, gcur, bstart, N, offs, srcs, dis);

    // layers
    k_l0  <<<((size_t)N * 32 + WG - 1) / WG, WG, 0, stream>>>(an, pos, W0, dis, bufA, N);
    k_agg <<<(N + 15) / 16, WG, 0, stream>>>(bufA, b0, dis, offs, srcs, bufB, N);
    k_gemm<<<(N + 63) / 64, WG, 0, stream>>>(bufB, W1, dis, bufA, N);
    k_agg <<<(N + 15) / 16, WG, 0, stream>>>(bufA, b1, dis, offs, srcs, bufB, N);
    k_gemm<<<(N + 63) / 64, WG, 0, stream>>>(bufB, W2, dis, bufA, N);
    k_agg <<<(N + 15) / 16, WG, 0, stream>>>(bufA, b2, dis, offs, srcs, bufB, N);

    // pool + head
    k_pool<<<64 * 8, WG, 0, stream>>>(bufB, batch, pooled, N);
    k_head<<<1, 64, 0, stream>>>(pooled, batch, linW, linb, (float*)d_out, N);
}

// Round 4
// 541.807 us; speedup vs baseline: 1.9369x; 1.0083x over previous
//
#include <hip/hip_runtime.h>
#include <hip/hip_fp16.h>
#include <math.h>

#define WG 256
#define NB 256             // radix buckets (node-range 512 each -> N <= 131072)
#define BSHIFT 9
#define NBLK 512           // partition blocks

__device__ __forceinline__ int lower_bound_i(const int* __restrict__ a, int n, int key) {
    int lo = 0, hi = n;
    while (lo < hi) { int mid = (lo + hi) >> 1; if (a[mid] < key) lo = mid + 1; else hi = mid; }
    return lo;
}

// half8 <-> float8 helpers (raw = 16B of 8 halves)
__device__ __forceinline__ void h8_to_f8(const float4 raw, float* f) {
    union { float s; __half2 h; } u;
    u.s = raw.x; float2 a = __half22float2(u.h);
    u.s = raw.y; float2 b = __half22float2(u.h);
    u.s = raw.z; float2 c = __half22float2(u.h);
    u.s = raw.w; float2 d = __half22float2(u.h);
    f[0]=a.x; f[1]=a.y; f[2]=b.x; f[3]=b.y; f[4]=c.x; f[5]=c.y; f[6]=d.x; f[7]=d.y;
}
__device__ __forceinline__ float4 f8_to_h8(const float* f) {
    union { float s; __half2 h; } u;
    float4 r;
    u.h = __floats2half2_rn(f[0], f[1]); r.x = u.s;
    u.h = __floats2half2_rn(f[2], f[3]); r.y = u.s;
    u.h = __floats2half2_rn(f[4], f[5]); r.z = u.s;
    u.h = __floats2half2_rn(f[6], f[7]); r.w = u.s;
    return r;
}
__device__ __forceinline__ float4 h4_to_f4(const float2 raw) {
    union { float s; __half2 h; } u;
    u.s = raw.x; float2 a = __half22float2(u.h);
    u.s = raw.y; float2 b = __half22float2(u.h);
    return make_float4(a.x, a.y, b.x, b.y);
}
__device__ __forceinline__ float2 f4_to_h4(const float4 v) {
    union { float s; __half2 h; } u;
    float2 r;
    u.h = __floats2half2_rn(v.x, v.y); r.x = u.s;
    u.h = __floats2half2_rn(v.z, v.w); r.y = u.s;
    return r;
}

// ---- CSR build: deterministic radix partition (no global atomics) ----------

// phase A: per-block bucket histogram -> gcounts[bucket * NBLK + block]
__global__ __launch_bounds__(256) void k_cnt(const int* __restrict__ edst, int E,
                                             int* __restrict__ gcounts) {
    __shared__ int hist[NB];
    int t = threadIdx.x, blk = blockIdx.x;
    if (t < NB) hist[t] = 0;
    __syncthreads();
    int chunk = (E + NBLK - 1) / NBLK;
    int e0 = blk * chunk, e1 = min(E, e0 + chunk);
    for (int e = e0 + t; e < e1; e += 256) atomicAdd(&hist[edst[e] >> BSHIFT], 1);
    __syncthreads();
    if (t < NB) gcounts[t * NBLK + blk] = hist[t];
}

// phase B: exclusive scan of the NB*NBLK matrix in place (one block, 1024 thr)
__global__ __launch_bounds__(1024) void k_scan_mat(int* __restrict__ gcounts) {
    __shared__ int part[1024];
    const int M = NB * NBLK;            // 131072
    const int PER = M / 1024;           // 128
    int t = threadIdx.x;
    int base = t * PER;
    int s = 0;
    for (int i = 0; i < PER; i++) s += gcounts[base + i];
    part[t] = s;
    __syncthreads();
    for (int d = 1; d < 1024; d <<= 1) {
        int a = (t >= d) ? part[t - d] : 0;
        __syncthreads();
        part[t] += a;
        __syncthreads();
    }
    int run = part[t] - s;              // exclusive prefix of this thread's span
    for (int i = 0; i < PER; i++) {
        int v = gcounts[base + i];
        gcounts[base + i] = run;
        run += v;
    }
}

// phase C: scatter edges to bucket-contiguous pairs via LDS cursors
__global__ __launch_bounds__(256) void k_scat(const int* __restrict__ esrc,
        const int* __restrict__ edst, int E,
        const int* __restrict__ gcounts, int2* __restrict__ pairs) {
    __shared__ int cur[NB];
    int t = threadIdx.x, blk = blockIdx.x;
    if (t < NB) cur[t] = gcounts[t * NBLK + blk];
    __syncthreads();
    int chunk = (E + NBLK - 1) / NBLK;
    int e0 = blk * chunk, e1 = min(E, e0 + chunk);
    for (int e = e0 + t; e < e1; e += 256) {
        int d = edst[e], s = esrc[e];
        int pos = atomicAdd(&cur[d >> BSHIFT], 1);
        pairs[pos] = make_int2(s, d);
    }
}

// phase D: per-bucket histogram + scan + place (all in LDS); also offs/dis
__global__ __launch_bounds__(256) void k_build(const int2* __restrict__ pairs,
        const int* __restrict__ gcounts, int N, int E,
        int* __restrict__ offs, int* __restrict__ srcs, float* __restrict__ dis) {
    __shared__ int cnt[512];
    __shared__ int wtot[4];
    int b = blockIdx.x, t = threadIdx.x;
    int n0 = b << BSHIFT;
    cnt[2 * t] = 0; cnt[2 * t + 1] = 0;
    __syncthreads();
    int bs = gcounts[b * NBLK];
    int be = gcounts[(b + 1) * NBLK];   // valid: b+1 <= nb < NB
    int m = be - bs;
    const int2* pb = &pairs[bs];
    for (int i = t; i < m; i += 256) {
        int2 p = pb[i];
        atomicAdd(&cnt[p.y - n0], 1);
    }
    __syncthreads();
    int v0 = cnt[2 * t], v1 = cnt[2 * t + 1];
    int ts = v0 + v1;
    int lane = t & 63, wid = t >> 6;
    int x = ts;
    #pragma unroll
    for (int d = 1; d < 64; d <<= 1) { int y = __shfl_up(x, d); if (lane >= d) x += y; }
    if (lane == 63) wtot[wid] = x;
    __syncthreads();
    int woff = 0;
    for (int w = 0; w < wid; w++) woff += wtot[w];
    int excl = woff + x - ts;           // block-exclusive prefix
    int o0 = excl, o1 = excl + v0;
    cnt[2 * t] = o0; cnt[2 * t + 1] = o1;
    int n = n0 + 2 * t;
    if (n + 0 < N) { offs[n + 0] = bs + o0; dis[n + 0] = rsqrtf((float)(v0 + 1)); }
    if (n + 1 < N) { offs[n + 1] = bs + o1; dis[n + 1] = rsqrtf((float)(v1 + 1)); }
    if (b == gridDim.x - 1 && t == 255) offs[N] = E;
    __syncthreads();
    for (int i = t; i < m; i += 256) {
        int2 p = pb[i];
        int pos = atomicAdd(&cnt[p.y - n0], 1);
        srcs[bs + pos] = p.x;
    }
}

// ---- Layer kernels --------------------------------------------------------

// layer0: h'[n][f] = (x0[n] @ W0)[f] * dis[n], stored fp16
__global__ void k_l0(const float* __restrict__ an, const float* __restrict__ pos,
                     const float* __restrict__ W0, const float* __restrict__ dis,
                     __half* __restrict__ h, int N) {
    int idx = blockIdx.x * blockDim.x + threadIdx.x;
    int n = idx >> 5, fq = idx & 31;
    if (n >= N) return;
    float a = an[n];
    float px = pos[n * 3 + 0], py = pos[n * 3 + 1], pz = pos[n * 3 + 2];
    float dn = dis[n];
    const float4 w0 = *(const float4*)&W0[0 * 128 + 4 * fq];
    const float4 w1 = *(const float4*)&W0[1 * 128 + 4 * fq];
    const float4 w2 = *(const float4*)&W0[2 * 128 + 4 * fq];
    const float4 w3 = *(const float4*)&W0[3 * 128 + 4 * fq];
    float4 r;
    r.x = (a * w0.x + px * w1.x + py * w2.x + pz * w3.x) * dn;
    r.y = (a * w0.y + px * w1.y + py * w2.y + pz * w3.y) * dn;
    r.z = (a * w0.z + px * w1.z + py * w2.z + pz * w3.z) * dn;
    r.w = (a * w0.w + px * w1.w + py * w2.w + pz * w3.w) * dn;
    *(float2*)&h[(size_t)n * 128 + 4 * fq] = f4_to_h4(r);
}

// h'[n][f] = (relu(x[n]) @ W)[f] * dis[n]; x fp16 staged to fp32 LDS tile
__global__ __launch_bounds__(256) void k_gemm(const __half* __restrict__ x,
                                              const float* __restrict__ W,
                                              const float* __restrict__ dis,
                                              __half* __restrict__ h, int N) {
    __shared__ float xs[64 * 128];
    int t = threadIdx.x;
    int n0 = blockIdx.x * 64;

    const uint2* xg = (const uint2*)(x + (size_t)n0 * 128);
    float4* xsv = (float4*)xs;
    int valid = min(64, N - n0) * 32;
#pragma unroll
    for (int i = 0; i < 8; i++) {
        int idx = t + i * 256;
        float4 v = make_float4(0.f, 0.f, 0.f, 0.f);
        if (idx < valid) {
            uint2 raw = xg[idx];
            float2 praw = make_float2(__uint_as_float(raw.x), __uint_as_float(raw.y));
            v = h4_to_f4(praw);
        }
        v.x = fmaxf(v.x, 0.f); v.y = fmaxf(v.y, 0.f);
        v.z = fmaxf(v.z, 0.f); v.w = fmaxf(v.w, 0.f);
        xsv[idx] = v;
    }
    __syncthreads();

    int fq = t & 31;
    int ng = t >> 5;
    const float* xrow = &xs[(ng * 8) * 128];

    float acc[8][4];
#pragma unroll
    for (int i = 0; i < 8; i++)
#pragma unroll
        for (int c = 0; c < 4; c++) acc[i][c] = 0.f;

#pragma unroll 2
    for (int kk = 0; kk < 128; kk += 4) {
        float4 w[4];
#pragma unroll
        for (int j = 0; j < 4; j++) w[j] = *(const float4*)&W[(kk + j) * 128 + 4 * fq];
#pragma unroll
        for (int i = 0; i < 8; i++) {
            float4 xv = *(const float4*)&xrow[i * 128 + kk];
            acc[i][0] += xv.x * w[0].x + xv.y * w[1].x + xv.z * w[2].x + xv.w * w[3].x;
            acc[i][1] += xv.x * w[0].y + xv.y * w[1].y + xv.z * w[2].y + xv.w * w[3].y;
            acc[i][2] += xv.x * w[0].z + xv.y * w[1].z + xv.z * w[2].z + xv.w * w[3].z;
            acc[i][3] += xv.x * w[0].w + xv.y * w[1].w + xv.z * w[2].w + xv.w * w[3].w;
        }
    }
#pragma unroll
    for (int i = 0; i < 8; i++) {
        int n = n0 + ng * 8 + i;
        if (n < N) {
            float dn = dis[n];
            float4 r = { acc[i][0] * dn, acc[i][1] * dn, acc[i][2] * dn, acc[i][3] * dn };
            *(float2*)&h[(size_t)n * 128 + 4 * fq] = f4_to_h4(r);
        }
    }
}

// agg[n] = b + dis[n] * (h'[n] + sum_src h'[src]); fp16 rows, fp32 accum
// block = 256 = 16 nodes x 16 lanes; lane handles 8 feats (16B loads); 8-deep MLP
__global__ __launch_bounds__(256) void k_agg(const __half* __restrict__ h,
                      const float* __restrict__ bias,
                      const float* __restrict__ dis, const int* __restrict__ offs,
                      const int* __restrict__ srcs, __half* __restrict__ agg, int N) {
    int fq = threadIdx.x & 15, ng = threadIdx.x >> 4;
    int n = blockIdx.x * 16 + ng;
    if (n >= N) return;
    float acc[8], tmp[8];
    {
        float4 raw = *(const float4*)&h[(size_t)n * 128 + 8 * fq];  // self-loop term
        h8_to_f8(raw, acc);
    }
    int e0 = offs[n], e1 = offs[n + 1];
    int e = e0;
    for (; e + 8 <= e1; e += 8) {
        int s0 = srcs[e + 0], s1 = srcs[e + 1], s2 = srcs[e + 2], s3 = srcs[e + 3];
        int s4 = srcs[e + 4], s5 = srcs[e + 5], s6 = srcs[e + 6], s7 = srcs[e + 7];
        float4 r0 = *(const float4*)&h[(size_t)s0 * 128 + 8 * fq];
        float4 r1 = *(const float4*)&h[(size_t)s1 * 128 + 8 * fq];
        float4 r2 = *(const float4*)&h[(size_t)s2 * 128 + 8 * fq];
        float4 r3 = *(const float4*)&h[(size_t)s3 * 128 + 8 * fq];
        float4 r4 = *(const float4*)&h[(size_t)s4 * 128 + 8 * fq];
        float4 r5 = *(const float4*)&h[(size_t)s5 * 128 + 8 * fq];
        float4 r6 = *(const float4*)&h[(size_t)s6 * 128 + 8 * fq];
        float4 r7 = *(const float4*)&h[(size_t)s7 * 128 + 8 * fq];
        h8_to_f8(r0, tmp);
#pragma unroll
        for (int k = 0; k < 8; k++) acc[k] += tmp[k];
        h8_to_f8(r1, tmp);
#pragma unroll
        for (int k = 0; k < 8; k++) acc[k] += tmp[k];
        h8_to_f8(r2, tmp);
#pragma unroll
        for (int k = 0; k < 8; k++) acc[k] += tmp[k];
        h8_to_f8(r3, tmp);
#pragma unroll
        for (int k = 0; k < 8; k++) acc[k] += tmp[k];
        h8_to_f8(r4, tmp);
#pragma unroll
        for (int k = 0; k < 8; k++) acc[k] += tmp[k];
        h8_to_f8(r5, tmp);
#pragma unroll
        for (int k = 0; k < 8; k++) acc[k] += tmp[k];
        h8_to_f8(r6, tmp);
#pragma unroll
        for (int k = 0; k < 8; k++) acc[k] += tmp[k];
        h8_to_f8(r7, tmp);
#pragma unroll
        for (int k = 0; k < 8; k++) acc[k] += tmp[k];
    }
    for (; e < e1; ++e) {
        int s = srcs[e];
        float4 r0 = *(const float4*)&h[(size_t)s * 128 + 8 * fq];
        h8_to_f8(r0, tmp);
#pragma unroll
        for (int k = 0; k < 8; k++) acc[k] += tmp[k];
    }
    float dn = dis[n];
    const float4 bv0 = *(const float4*)&bias[8 * fq];
    const float4 bv1 = *(const float4*)&bias[8 * fq + 4];
    float outv[8];
    outv[0] = bv0.x + dn * acc[0]; outv[1] = bv0.y + dn * acc[1];
    outv[2] = bv0.z + dn * acc[2]; outv[3] = bv0.w + dn * acc[3];
    outv[4] = bv1.x + dn * acc[4]; outv[5] = bv1.y + dn * acc[5];
    outv[6] = bv1.z + dn * acc[6]; outv[7] = bv1.w + dn * acc[7];
    *(float4*)&agg[(size_t)n * 128 + 8 * fq] = f8_to_h8(outv);
}

// ---- Pool + head ----------------------------------------------------------

__global__ void k_pool(const __half* __restrict__ x, const int* __restrict__ batch,
                       float* __restrict__ pooled, int N) {
    int g = blockIdx.x >> 3, c = blockIdx.x & 7;
    int start = lower_bound_i(batch, N, g);
    int end   = lower_bound_i(batch, N, g + 1);
    int len = end - start;
    int cb = start + (int)((long)len * c / 8);
    int ce = start + (int)((long)len * (c + 1) / 8);
    int f = threadIdx.x & 127, half = threadIdx.x >> 7;
    float acc = 0.f;
    for (int n = cb + half; n < ce; n += 2) acc += fmaxf(__half2float(x[(size_t)n * 128 + f]), 0.f);
    __shared__ float sh[128];
    if (half == 1) sh[f] = acc;
    __syncthreads();
    if (half == 0) atomicAdd(&pooled[g * 128 + f], acc + sh[f]);
}

__global__ void k_head(const float* __restrict__ pooled, const int* __restrict__ batch,
                       const float* __restrict__ linW, const float* __restrict__ linb,
                       float* __restrict__ out, int N) {
    int g = threadIdx.x;
    if (g >= 64) return;
    int start = lower_bound_i(batch, N, g);
    int end   = lower_bound_i(batch, N, g + 1);
    float cnt = fmaxf((float)(end - start), 1.0f);
    float logits[8];
#pragma unroll
    for (int j = 0; j < 8; j++) logits[j] = linb[j];
    for (int f = 0; f < 128; f++) {
        float p = pooled[g * 128 + f] / cnt;
#pragma unroll
        for (int j = 0; j < 8; j++) logits[j] += p * linW[f * 8 + j];
    }
    float m = logits[0];
#pragma unroll
    for (int j = 1; j < 8; j++) m = fmaxf(m, logits[j]);
    float s = 0.f;
    float e[8];
#pragma unroll
    for (int j = 0; j < 8; j++) { e[j] = expf(logits[j] - m); s += e[j]; }
#pragma unroll
    for (int j = 0; j < 8; j++) out[g * 8 + j] = e[j] / s;
}

// ---- Launch ---------------------------------------------------------------

extern "C" void kernel_launch(void* const* d_in, const int* in_sizes, int n_in,
                              void* d_out, int out_size, void* d_ws, size_t ws_size,
                              hipStream_t stream) {
    const float* an   = (const float*)d_in[0];
    const float* pos  = (const float*)d_in[1];
    const float* W0   = (const float*)d_in[2];
    const float* b0   = (const float*)d_in[3];
    const float* W1   = (const float*)d_in[4];
    const float* b1   = (const float*)d_in[5];
    const float* W2   = (const float*)d_in[6];
    const float* b2   = (const float*)d_in[7];
    const float* linW = (const float*)d_in[8];
    const float* linb = (const float*)d_in[9];
    const int*   ei   = (const int*)d_in[10];
    const int*   batch= (const int*)d_in[11];

    int N = in_sizes[0];
    int E = in_sizes[10] / 2;
    const int* esrc = ei;
    const int* edst = ei + E;
    int nb = (N + (1 << BSHIFT) - 1) >> BSHIFT;   // 196 for N=100000

    char* p = (char*)d_ws;
    auto carve = [&](size_t bytes) -> void* {
        void* r = (void*)p;
        p += (bytes + 255) & ~(size_t)255;
        return r;
    };
    __half* bufA  = (__half*)carve((size_t)N * 128 * 2);
    __half* bufB  = (__half*)carve((size_t)N * 128 * 2);
    float* dis    = (float*)carve((size_t)N * 4);
    int*   offs   = (int*)  carve((size_t)(N + 1) * 4);
    int*   srcs   = (int*)  carve((size_t)E * 4);
    int2*  pairs  = (int2*) carve((size_t)E * 8);
    int*   gcounts= (int*)  carve((size_t)NB * NBLK * 4);
    float* pooled = (float*)carve(64 * 128 * 4);

    hipMemsetAsync(pooled, 0, 64 * 128 * 4, stream);

    // CSR build: deterministic radix partition + per-bucket LDS build
    k_cnt     <<<NBLK, WG, 0, stream>>>(edst, E, gcounts);
    k_scan_mat<<<1, 1024, 0, stream>>>(gcounts);
    k_scat    <<<NBLK, WG, 0, stream>>>(esrc, edst, E, gcounts, pairs);
    k_build   <<<nb, WG, 0, stream>>>(pairs, gcounts, N, E, offs, srcs, dis);

    // layers
    k_l0  <<<((size_t)N * 32 + WG - 1) / WG, WG, 0, stream>>>(an, pos, W0, dis, bufA, N);
    k_agg <<<(N + 15) / 16, WG, 0, stream>>>(bufA, b0, dis, offs, srcs, bufB, N);
    k_gemm<<<(N + 63) / 64, WG, 0, stream>>>(bufB, W1, dis, bufA, N);
    k_agg <<<(N + 15) / 16, WG, 0, stream>>>(bufA, b1, dis, offs, srcs, bufB, N);
    k_gemm<<<(N + 63) / 64, WG, 0, stream>>>(bufB, W2, dis, bufA, N);
    k_agg <<<(N + 15) / 16, WG, 0, stream>>>(bufA, b2, dis, offs, srcs, bufB, N);

    // pool + head
    k_pool<<<64 * 8, WG, 0, stream>>>(bufB, batch, pooled, N);
    k_head<<<1, 64, 0, stream>>>(pooled, batch, linW, linb, (float*)d_out, N);
}

// Round 5
// 464.646 us; speedup vs baseline: 2.2585x; 1.1661x over previous
//
#include <hip/hip_runtime.h>
#include <math.h>

#define WG 256
#define NB 256             // radix buckets (node-range 512 each -> N <= 131072)
#define BSHIFT 9
#define NBLK 512           // partition blocks

typedef float vf2 __attribute__((ext_vector_type(2)));

__device__ __forceinline__ int lower_bound_i(const int* __restrict__ a, int n, int key) {
    int lo = 0, hi = n;
    while (lo < hi) { int mid = (lo + hi) >> 1; if (a[mid] < key) lo = mid + 1; else hi = mid; }
    return lo;
}

// ---- fp8 (OCP e4m3) helpers ------------------------------------------------
// 8 fp8 packed in uint2 -> 8 floats
__device__ __forceinline__ void fp8x8_to_f8(uint2 raw, float* f) {
    vf2 a = __builtin_amdgcn_cvt_pk_f32_fp8((int)raw.x, false);
    vf2 b = __builtin_amdgcn_cvt_pk_f32_fp8((int)raw.x, true);
    vf2 c = __builtin_amdgcn_cvt_pk_f32_fp8((int)raw.y, false);
    vf2 d = __builtin_amdgcn_cvt_pk_f32_fp8((int)raw.y, true);
    f[0]=a.x; f[1]=a.y; f[2]=b.x; f[3]=b.y; f[4]=c.x; f[5]=c.y; f[6]=d.x; f[7]=d.y;
}
// 4 floats -> 4 fp8 packed in uint
__device__ __forceinline__ unsigned int f4_to_fp8x4(float x, float y, float z, float w) {
    int v = __builtin_amdgcn_cvt_pk_fp8_f32(x, y, 0, false);
    v = __builtin_amdgcn_cvt_pk_fp8_f32(z, w, v, true);
    return (unsigned int)v;
}

// ---- CSR build: deterministic radix partition (no global atomics) ----------

__global__ __launch_bounds__(256) void k_cnt(const int* __restrict__ edst, int E,
                                             int* __restrict__ gcounts) {
    __shared__ int hist[NB];
    int t = threadIdx.x, blk = blockIdx.x;
    if (t < NB) hist[t] = 0;
    __syncthreads();
    int chunk = (E + NBLK - 1) / NBLK;
    int e0 = blk * chunk, e1 = min(E, e0 + chunk);
    for (int e = e0 + t; e < e1; e += 256) atomicAdd(&hist[edst[e] >> BSHIFT], 1);
    __syncthreads();
    if (t < NB) gcounts[t * NBLK + blk] = hist[t];
}

__global__ __launch_bounds__(1024) void k_scan_mat(int* __restrict__ gcounts) {
    __shared__ int part[1024];
    const int M = NB * NBLK;            // 131072
    const int PER = M / 1024;           // 128
    int t = threadIdx.x;
    int base = t * PER;
    int s = 0;
    for (int i = 0; i < PER; i++) s += gcounts[base + i];
    part[t] = s;
    __syncthreads();
    for (int d = 1; d < 1024; d <<= 1) {
        int a = (t >= d) ? part[t - d] : 0;
        __syncthreads();
        part[t] += a;
        __syncthreads();
    }
    int run = part[t] - s;
    for (int i = 0; i < PER; i++) {
        int v = gcounts[base + i];
        gcounts[base + i] = run;
        run += v;
    }
}

__global__ __launch_bounds__(256) void k_scat(const int* __restrict__ esrc,
        const int* __restrict__ edst, int E,
        const int* __restrict__ gcounts, int2* __restrict__ pairs) {
    __shared__ int cur[NB];
    int t = threadIdx.x, blk = blockIdx.x;
    if (t < NB) cur[t] = gcounts[t * NBLK + blk];
    __syncthreads();
    int chunk = (E + NBLK - 1) / NBLK;
    int e0 = blk * chunk, e1 = min(E, e0 + chunk);
    for (int e = e0 + t; e < e1; e += 256) {
        int d = edst[e], s = esrc[e];
        int pos = atomicAdd(&cur[d >> BSHIFT], 1);
        pairs[pos] = make_int2(s, d);
    }
}

__global__ __launch_bounds__(256) void k_build(const int2* __restrict__ pairs,
        const int* __restrict__ gcounts, int N, int E,
        int* __restrict__ offs, int* __restrict__ srcs, float* __restrict__ dis) {
    __shared__ int cnt[512];
    __shared__ int wtot[4];
    int b = blockIdx.x, t = threadIdx.x;
    int n0 = b << BSHIFT;
    cnt[2 * t] = 0; cnt[2 * t + 1] = 0;
    __syncthreads();
    int bs = gcounts[b * NBLK];
    int be = gcounts[(b + 1) * NBLK];
    int m = be - bs;
    const int2* pb = &pairs[bs];
    for (int i = t; i < m; i += 256) {
        int2 p = pb[i];
        atomicAdd(&cnt[p.y - n0], 1);
    }
    __syncthreads();
    int v0 = cnt[2 * t], v1 = cnt[2 * t + 1];
    int ts = v0 + v1;
    int lane = t & 63, wid = t >> 6;
    int x = ts;
    #pragma unroll
    for (int d = 1; d < 64; d <<= 1) { int y = __shfl_up(x, d); if (lane >= d) x += y; }
    if (lane == 63) wtot[wid] = x;
    __syncthreads();
    int woff = 0;
    for (int w = 0; w < wid; w++) woff += wtot[w];
    int excl = woff + x - ts;
    int o0 = excl, o1 = excl + v0;
    cnt[2 * t] = o0; cnt[2 * t + 1] = o1;
    int n = n0 + 2 * t;
    if (n + 0 < N) { offs[n + 0] = bs + o0; dis[n + 0] = rsqrtf((float)(v0 + 1)); }
    if (n + 1 < N) { offs[n + 1] = bs + o1; dis[n + 1] = rsqrtf((float)(v1 + 1)); }
    if (b == gridDim.x - 1 && t == 255) offs[N] = E;
    __syncthreads();
    for (int i = t; i < m; i += 256) {
        int2 p = pb[i];
        int pos = atomicAdd(&cnt[p.y - n0], 1);
        srcs[bs + pos] = p.x;
    }
}

// ---- Layer kernels --------------------------------------------------------

// layer0: h'[n][f] = (x0[n] @ W0)[f] * dis[n], stored fp8
__global__ void k_l0(const float* __restrict__ an, const float* __restrict__ pos,
                     const float* __restrict__ W0, const float* __restrict__ dis,
                     unsigned int* __restrict__ h, int N) {
    int idx = blockIdx.x * blockDim.x + threadIdx.x;
    int n = idx >> 5, fq = idx & 31;
    if (n >= N) return;
    float a = an[n];
    float px = pos[n * 3 + 0], py = pos[n * 3 + 1], pz = pos[n * 3 + 2];
    float dn = dis[n];
    const float4 w0 = *(const float4*)&W0[0 * 128 + 4 * fq];
    const float4 w1 = *(const float4*)&W0[1 * 128 + 4 * fq];
    const float4 w2 = *(const float4*)&W0[2 * 128 + 4 * fq];
    const float4 w3 = *(const float4*)&W0[3 * 128 + 4 * fq];
    float4 r;
    r.x = (a * w0.x + px * w1.x + py * w2.x + pz * w3.x) * dn;
    r.y = (a * w0.y + px * w1.y + py * w2.y + pz * w3.y) * dn;
    r.z = (a * w0.z + px * w1.z + py * w2.z + pz * w3.z) * dn;
    r.w = (a * w0.w + px * w1.w + py * w2.w + pz * w3.w) * dn;
    h[(size_t)n * 32 + fq] = f4_to_fp8x4(r.x, r.y, r.z, r.w);
}

// h'[n][f] = (relu(x[n]) @ W)[f] * dis[n]; x fp8 staged to fp32 LDS tile
__global__ __launch_bounds__(256) void k_gemm(const unsigned int* __restrict__ x,
                                              const float* __restrict__ W,
                                              const float* __restrict__ dis,
                                              unsigned int* __restrict__ h, int N) {
    __shared__ float xs[64 * 128];
    int t = threadIdx.x;
    int n0 = blockIdx.x * 64;

    const uint2* xg = (const uint2*)(x + (size_t)n0 * 32);   // 8 fp8 per uint2
    int valid = min(64, N - n0) * 16;                        // uint2 per tile
#pragma unroll
    for (int i = 0; i < 4; i++) {
        int idx = t + i * 256;
        float f[8];
        if (idx < valid) {
            fp8x8_to_f8(xg[idx], f);
#pragma unroll
            for (int k = 0; k < 8; k++) f[k] = fmaxf(f[k], 0.f);
        } else {
#pragma unroll
            for (int k = 0; k < 8; k++) f[k] = 0.f;
        }
        float* dst = &xs[idx * 8];
        *(float4*)dst = make_float4(f[0], f[1], f[2], f[3]);
        *(float4*)(dst + 4) = make_float4(f[4], f[5], f[6], f[7]);
    }
    __syncthreads();

    int fq = t & 31;
    int ng = t >> 5;
    const float* xrow = &xs[(ng * 8) * 128];

    float acc[8][4];
#pragma unroll
    for (int i = 0; i < 8; i++)
#pragma unroll
        for (int c = 0; c < 4; c++) acc[i][c] = 0.f;

#pragma unroll 2
    for (int kk = 0; kk < 128; kk += 4) {
        float4 w[4];
#pragma unroll
        for (int j = 0; j < 4; j++) w[j] = *(const float4*)&W[(kk + j) * 128 + 4 * fq];
#pragma unroll
        for (int i = 0; i < 8; i++) {
            float4 xv = *(const float4*)&xrow[i * 128 + kk];
            acc[i][0] += xv.x * w[0].x + xv.y * w[1].x + xv.z * w[2].x + xv.w * w[3].x;
            acc[i][1] += xv.x * w[0].y + xv.y * w[1].y + xv.z * w[2].y + xv.w * w[3].y;
            acc[i][2] += xv.x * w[0].z + xv.y * w[1].z + xv.z * w[2].z + xv.w * w[3].z;
            acc[i][3] += xv.x * w[0].w + xv.y * w[1].w + xv.z * w[2].w + xv.w * w[3].w;
        }
    }
#pragma unroll
    for (int i = 0; i < 8; i++) {
        int n = n0 + ng * 8 + i;
        if (n < N) {
            float dn = dis[n];
            h[(size_t)n * 32 + fq] =
                f4_to_fp8x4(acc[i][0] * dn, acc[i][1] * dn, acc[i][2] * dn, acc[i][3] * dn);
        }
    }
}

// agg[n] = b + dis[n] * (h'[n] + sum_src h'[src]); fp8 rows, fp32 accum
// block = 256 = 16 nodes x 16 lanes; lane handles 8 feats (8B loads); 8-deep MLP
__global__ __launch_bounds__(256) void k_agg(const unsigned int* __restrict__ h,
                      const float* __restrict__ bias,
                      const float* __restrict__ dis, const int* __restrict__ offs,
                      const int* __restrict__ srcs, unsigned int* __restrict__ agg, int N) {
    int fq = threadIdx.x & 15, ng = threadIdx.x >> 4;
    int n = blockIdx.x * 16 + ng;
    if (n >= N) return;
    const uint2* hp = (const uint2*)h;   // row = 16 uint2
    float acc[8], tmp[8];
    fp8x8_to_f8(hp[(size_t)n * 16 + fq], acc);   // self-loop term
    int e0 = offs[n], e1 = offs[n + 1];
    int e = e0;
    for (; e + 8 <= e1; e += 8) {
        int s0 = srcs[e + 0], s1 = srcs[e + 1], s2 = srcs[e + 2], s3 = srcs[e + 3];
        int s4 = srcs[e + 4], s5 = srcs[e + 5], s6 = srcs[e + 6], s7 = srcs[e + 7];
        uint2 r0 = hp[(size_t)s0 * 16 + fq];
        uint2 r1 = hp[(size_t)s1 * 16 + fq];
        uint2 r2 = hp[(size_t)s2 * 16 + fq];
        uint2 r3 = hp[(size_t)s3 * 16 + fq];
        uint2 r4 = hp[(size_t)s4 * 16 + fq];
        uint2 r5 = hp[(size_t)s5 * 16 + fq];
        uint2 r6 = hp[(size_t)s6 * 16 + fq];
        uint2 r7 = hp[(size_t)s7 * 16 + fq];
        fp8x8_to_f8(r0, tmp);
#pragma unroll
        for (int k = 0; k < 8; k++) acc[k] += tmp[k];
        fp8x8_to_f8(r1, tmp);
#pragma unroll
        for (int k = 0; k < 8; k++) acc[k] += tmp[k];
        fp8x8_to_f8(r2, tmp);
#pragma unroll
        for (int k = 0; k < 8; k++) acc[k] += tmp[k];
        fp8x8_to_f8(r3, tmp);
#pragma unroll
        for (int k = 0; k < 8; k++) acc[k] += tmp[k];
        fp8x8_to_f8(r4, tmp);
#pragma unroll
        for (int k = 0; k < 8; k++) acc[k] += tmp[k];
        fp8x8_to_f8(r5, tmp);
#pragma unroll
        for (int k = 0; k < 8; k++) acc[k] += tmp[k];
        fp8x8_to_f8(r6, tmp);
#pragma unroll
        for (int k = 0; k < 8; k++) acc[k] += tmp[k];
        fp8x8_to_f8(r7, tmp);
#pragma unroll
        for (int k = 0; k < 8; k++) acc[k] += tmp[k];
    }
    for (; e < e1; ++e) {
        int s = srcs[e];
        fp8x8_to_f8(hp[(size_t)s * 16 + fq], tmp);
#pragma unroll
        for (int k = 0; k < 8; k++) acc[k] += tmp[k];
    }
    float dn = dis[n];
    const float4 bv0 = *(const float4*)&bias[8 * fq];
    const float4 bv1 = *(const float4*)&bias[8 * fq + 4];
    unsigned int lo = f4_to_fp8x4(bv0.x + dn * acc[0], bv0.y + dn * acc[1],
                                  bv0.z + dn * acc[2], bv0.w + dn * acc[3]);
    unsigned int hi = f4_to_fp8x4(bv1.x + dn * acc[4], bv1.y + dn * acc[5],
                                  bv1.z + dn * acc[6], bv1.w + dn * acc[7]);
    uint2 outv = make_uint2(lo, hi);
    *(uint2*)&agg[(size_t)n * 32 + 2 * fq] = outv;
}

// ---- Pool + head ----------------------------------------------------------

__global__ void k_pool(const unsigned char* __restrict__ x, const int* __restrict__ batch,
                       float* __restrict__ pooled, int N) {
    int g = blockIdx.x >> 3, c = blockIdx.x & 7;
    int start = lower_bound_i(batch, N, g);
    int end   = lower_bound_i(batch, N, g + 1);
    int len = end - start;
    int cb = start + (int)((long)len * c / 8);
    int ce = start + (int)((long)len * (c + 1) / 8);
    int f = threadIdx.x & 127, half = threadIdx.x >> 7;
    float acc = 0.f;
    for (int n = cb + half; n < ce; n += 2) {
        int b = x[(size_t)n * 128 + f];
        vf2 v = __builtin_amdgcn_cvt_pk_f32_fp8(b, false);
        acc += fmaxf(v.x, 0.f);
    }
    __shared__ float sh[128];
    if (half == 1) sh[f] = acc;
    __syncthreads();
    if (half == 0) atomicAdd(&pooled[g * 128 + f], acc + sh[f]);
}

__global__ void k_head(const float* __restrict__ pooled, const int* __restrict__ batch,
                       const float* __restrict__ linW, const float* __restrict__ linb,
                       float* __restrict__ out, int N) {
    int g = threadIdx.x;
    if (g >= 64) return;
    int start = lower_bound_i(batch, N, g);
    int end   = lower_bound_i(batch, N, g + 1);
    float cnt = fmaxf((float)(end - start), 1.0f);
    float logits[8];
#pragma unroll
    for (int j = 0; j < 8; j++) logits[j] = linb[j];
    for (int f = 0; f < 128; f++) {
        float p = pooled[g * 128 + f] / cnt;
#pragma unroll
        for (int j = 0; j < 8; j++) logits[j] += p * linW[f * 8 + j];
    }
    float m = logits[0];
#pragma unroll
    for (int j = 1; j < 8; j++) m = fmaxf(m, logits[j]);
    float s = 0.f;
    float e[8];
#pragma unroll
    for (int j = 0; j < 8; j++) { e[j] = expf(logits[j] - m); s += e[j]; }
#pragma unroll
    for (int j = 0; j < 8; j++) out[g * 8 + j] = e[j] / s;
}

// ---- Launch ---------------------------------------------------------------

extern "C" void kernel_launch(void* const* d_in, const int* in_sizes, int n_in,
                              void* d_out, int out_size, void* d_ws, size_t ws_size,
                              hipStream_t stream) {
    const float* an   = (const float*)d_in[0];
    const float* pos  = (const float*)d_in[1];
    const float* W0   = (const float*)d_in[2];
    const float* b0   = (const float*)d_in[3];
    const float* W1   = (const float*)d_in[4];
    const float* b1   = (const float*)d_in[5];
    const float* W2   = (const float*)d_in[6];
    const float* b2   = (const float*)d_in[7];
    const float* linW = (const float*)d_in[8];
    const float* linb = (const float*)d_in[9];
    const int*   ei   = (const int*)d_in[10];
    const int*   batch= (const int*)d_in[11];

    int N = in_sizes[0];
    int E = in_sizes[10] / 2;
    const int* esrc = ei;
    const int* edst = ei + E;
    int nb = (N + (1 << BSHIFT) - 1) >> BSHIFT;   // 196 for N=100000

    char* p = (char*)d_ws;
    auto carve = [&](size_t bytes) -> void* {
        void* r = (void*)p;
        p += (bytes + 255) & ~(size_t)255;
        return r;
    };
    unsigned int* bufA = (unsigned int*)carve((size_t)N * 128);   // fp8 rows
    unsigned int* bufB = (unsigned int*)carve((size_t)N * 128);
    float* dis    = (float*)carve((size_t)N * 4);
    int*   offs   = (int*)  carve((size_t)(N + 1) * 4);
    int*   srcs   = (int*)  carve((size_t)E * 4);
    int2*  pairs  = (int2*) carve((size_t)E * 8);
    int*   gcounts= (int*)  carve((size_t)NB * NBLK * 4);
    float* pooled = (float*)carve(64 * 128 * 4);

    hipMemsetAsync(pooled, 0, 64 * 128 * 4, stream);

    // CSR build: deterministic radix partition + per-bucket LDS build
    k_cnt     <<<NBLK, WG, 0, stream>>>(edst, E, gcounts);
    k_scan_mat<<<1, 1024, 0, stream>>>(gcounts);
    k_scat    <<<NBLK, WG, 0, stream>>>(esrc, edst, E, gcounts, pairs);
    k_build   <<<nb, WG, 0, stream>>>(pairs, gcounts, N, E, offs, srcs, dis);

    // layers
    k_l0  <<<((size_t)N * 32 + WG - 1) / WG, WG, 0, stream>>>(an, pos, W0, dis, bufA, N);
    k_agg <<<(N + 15) / 16, WG, 0, stream>>>(bufA, b0, dis, offs, srcs, bufB, N);
    k_gemm<<<(N + 63) / 64, WG, 0, stream>>>(bufB, W1, dis, bufA, N);
    k_agg <<<(N + 15) / 16, WG, 0, stream>>>(bufA, b1, dis, offs, srcs, bufB, N);
    k_gemm<<<(N + 63) / 64, WG, 0, stream>>>(bufB, W2, dis, bufA, N);
    k_agg <<<(N + 15) / 16, WG, 0, stream>>>(bufA, b2, dis, offs, srcs, bufB, N);

    // pool + head
    k_pool<<<64 * 8, WG, 0, stream>>>((const unsigned char*)bufB, batch, pooled, N);
    k_head<<<1, 64, 0, stream>>>(pooled, batch, linW, linb, (float*)d_out, N);
}

// Round 6
// 391.479 us; speedup vs baseline: 2.6807x; 1.1869x over previous
//
#include <hip/hip_runtime.h>
#include <math.h>

#define WG 256
#define NB 256             // radix buckets (node-range 512 each -> N <= 131072)
#define BSHIFT 9
#define NBLK 512           // partition blocks

typedef float vf2 __attribute__((ext_vector_type(2)));
typedef short bf16x8 __attribute__((ext_vector_type(8)));
typedef float f32x4 __attribute__((ext_vector_type(4)));

#define XS_STRIDE 136      // ushort stride, 16B-aligned rows + conflict pad
#define WT_STRIDE 136
#define C_STRIDE 132       // float stride, 16B-aligned

__device__ __forceinline__ int lower_bound_i(const int* __restrict__ a, int n, int key) {
    int lo = 0, hi = n;
    while (lo < hi) { int mid = (lo + hi) >> 1; if (a[mid] < key) lo = mid + 1; else hi = mid; }
    return lo;
}

// ---- fp8 (OCP e4m3) helpers ------------------------------------------------
__device__ __forceinline__ void fp8x8_to_f8(uint2 raw, float* f) {
    vf2 a = __builtin_amdgcn_cvt_pk_f32_fp8((int)raw.x, false);
    vf2 b = __builtin_amdgcn_cvt_pk_f32_fp8((int)raw.x, true);
    vf2 c = __builtin_amdgcn_cvt_pk_f32_fp8((int)raw.y, false);
    vf2 d = __builtin_amdgcn_cvt_pk_f32_fp8((int)raw.y, true);
    f[0]=a.x; f[1]=a.y; f[2]=b.x; f[3]=b.y; f[4]=c.x; f[5]=c.y; f[6]=d.x; f[7]=d.y;
}
__device__ __forceinline__ unsigned int f4_to_fp8x4(float x, float y, float z, float w) {
    int v = __builtin_amdgcn_cvt_pk_fp8_f32(x, y, 0, false);
    v = __builtin_amdgcn_cvt_pk_fp8_f32(z, w, v, true);
    return (unsigned int)v;
}
// f32 -> bf16: truncation (exact for fp8-sourced values)
__device__ __forceinline__ unsigned short f_to_bf_trunc(float f) {
    return (unsigned short)(__float_as_uint(f) >> 16);
}
// f32 -> bf16 RNE (for W)
__device__ __forceinline__ unsigned short f_to_bf_rne(float f) {
    unsigned int u = __float_as_uint(f);
    u += 0x7FFFu + ((u >> 16) & 1u);
    return (unsigned short)(u >> 16);
}

// ---- CSR build: deterministic radix partition (no global atomics) ----------

__global__ __launch_bounds__(256) void k_cnt(const int* __restrict__ edst, int E,
                                             int* __restrict__ gcounts) {
    __shared__ int hist[NB];
    int t = threadIdx.x, blk = blockIdx.x;
    if (t < NB) hist[t] = 0;
    __syncthreads();
    int chunk = (E + NBLK - 1) / NBLK;
    int e0 = blk * chunk, e1 = min(E, e0 + chunk);
    for (int e = e0 + t; e < e1; e += 256) atomicAdd(&hist[edst[e] >> BSHIFT], 1);
    __syncthreads();
    if (t < NB) gcounts[t * NBLK + blk] = hist[t];
}

__global__ __launch_bounds__(1024) void k_scan_mat(int* __restrict__ gcounts) {
    __shared__ int part[1024];
    const int M = NB * NBLK;
    const int PER = M / 1024;           // 128
    int t = threadIdx.x;
    int base = t * PER;
    int s = 0;
    for (int i = 0; i < PER; i++) s += gcounts[base + i];
    part[t] = s;
    __syncthreads();
    for (int d = 1; d < 1024; d <<= 1) {
        int a = (t >= d) ? part[t - d] : 0;
        __syncthreads();
        part[t] += a;
        __syncthreads();
    }
    int run = part[t] - s;
    for (int i = 0; i < PER; i++) {
        int v = gcounts[base + i];
        gcounts[base + i] = run;
        run += v;
    }
}

// scatter edges packed as (src << 9) | (dst & 511)
__global__ __launch_bounds__(256) void k_scat(const int* __restrict__ esrc,
        const int* __restrict__ edst, int E,
        const int* __restrict__ gcounts, int* __restrict__ pairs) {
    __shared__ int cur[NB];
    int t = threadIdx.x, blk = blockIdx.x;
    if (t < NB) cur[t] = gcounts[t * NBLK + blk];
    __syncthreads();
    int chunk = (E + NBLK - 1) / NBLK;
    int e0 = blk * chunk, e1 = min(E, e0 + chunk);
    for (int e = e0 + t; e < e1; e += 256) {
        int d = edst[e], s = esrc[e];
        int pos = atomicAdd(&cur[d >> BSHIFT], 1);
        pairs[pos] = (s << BSHIFT) | (d & ((1 << BSHIFT) - 1));
    }
}

__global__ __launch_bounds__(256) void k_build(const int* __restrict__ pairs,
        const int* __restrict__ gcounts, int N, int E,
        int* __restrict__ offs, int* __restrict__ srcs, float* __restrict__ dis) {
    __shared__ int cnt[512];
    __shared__ int wtot[4];
    int b = blockIdx.x, t = threadIdx.x;
    int n0 = b << BSHIFT;
    cnt[2 * t] = 0; cnt[2 * t + 1] = 0;
    __syncthreads();
    int bs = gcounts[b * NBLK];
    int be = gcounts[(b + 1) * NBLK];
    int m = be - bs;
    const int* pb = &pairs[bs];
    for (int i = t; i < m; i += 256) {
        int p = pb[i];
        atomicAdd(&cnt[p & 511], 1);
    }
    __syncthreads();
    int v0 = cnt[2 * t], v1 = cnt[2 * t + 1];
    int ts = v0 + v1;
    int lane = t & 63, wid = t >> 6;
    int x = ts;
    #pragma unroll
    for (int d = 1; d < 64; d <<= 1) { int y = __shfl_up(x, d); if (lane >= d) x += y; }
    if (lane == 63) wtot[wid] = x;
    __syncthreads();
    int woff = 0;
    for (int w = 0; w < wid; w++) woff += wtot[w];
    int excl = woff + x - ts;
    int o0 = excl, o1 = excl + v0;
    cnt[2 * t] = o0; cnt[2 * t + 1] = o1;
    int n = n0 + 2 * t;
    if (n + 0 < N) { offs[n + 0] = bs + o0; dis[n + 0] = rsqrtf((float)(v0 + 1)); }
    if (n + 1 < N) { offs[n + 1] = bs + o1; dis[n + 1] = rsqrtf((float)(v1 + 1)); }
    if (b == gridDim.x - 1 && t == 255) offs[N] = E;
    __syncthreads();
    for (int i = t; i < m; i += 256) {
        int p = pb[i];
        int pos = atomicAdd(&cnt[p & 511], 1);
        srcs[bs + pos] = p >> BSHIFT;
    }
}

// ---- W transpose to bf16: WT[j][k] = bf16(W[k][j]) -------------------------
__global__ __launch_bounds__(256) void k_wt(const float* __restrict__ W,
                                            unsigned short* __restrict__ wt) {
    int idx = blockIdx.x * 256 + threadIdx.x;   // 64 blocks -> 16384
    int k = idx >> 7, j = idx & 127;
    float v = W[k * 128 + j];                   // coalesced read
    wt[j * 128 + k] = f_to_bf_rne(v);           // scattered 2B write (once)
}

// ---- Layer kernels --------------------------------------------------------

// layer0: h'[n][f] = (x0[n] @ W0)[f] * dis[n], stored fp8
__global__ void k_l0(const float* __restrict__ an, const float* __restrict__ pos,
                     const float* __restrict__ W0, const float* __restrict__ dis,
                     unsigned int* __restrict__ h, int N) {
    int idx = blockIdx.x * blockDim.x + threadIdx.x;
    int n = idx >> 5, fq = idx & 31;
    if (n >= N) return;
    float a = an[n];
    float px = pos[n * 3 + 0], py = pos[n * 3 + 1], pz = pos[n * 3 + 2];
    float dn = dis[n];
    const float4 w0 = *(const float4*)&W0[0 * 128 + 4 * fq];
    const float4 w1 = *(const float4*)&W0[1 * 128 + 4 * fq];
    const float4 w2 = *(const float4*)&W0[2 * 128 + 4 * fq];
    const float4 w3 = *(const float4*)&W0[3 * 128 + 4 * fq];
    float4 r;
    r.x = (a * w0.x + px * w1.x + py * w2.x + pz * w3.x) * dn;
    r.y = (a * w0.y + px * w1.y + py * w2.y + pz * w3.y) * dn;
    r.z = (a * w0.z + px * w1.z + py * w2.z + pz * w3.z) * dn;
    r.w = (a * w0.w + px * w1.w + py * w2.w + pz * w3.w) * dn;
    h[(size_t)n * 32 + fq] = f4_to_fp8x4(r.x, r.y, r.z, r.w);
}

// MFMA GEMM: h'[n][f] = (relu(x[n]) @ W)[f] * dis[n]
// block = 256 (4 waves); tile = 64 nodes x 128 feats; bf16 MFMA 16x16x32.
// A layout: A[m=lane&15][k=quad*8+j]; C/D: col=lane&15, row=quad*4+reg.
__global__ __launch_bounds__(256) void k_gemm(const unsigned int* __restrict__ x,
                                              const unsigned short* __restrict__ wt,
                                              const float* __restrict__ dis,
                                              unsigned int* __restrict__ h, int N) {
    __shared__ __align__(16) char ldsb[(64 * XS_STRIDE + 128 * WT_STRIDE) * 2];
    unsigned short* xs  = (unsigned short*)ldsb;          // [64][136] bf16
    unsigned short* wtl = xs + 64 * XS_STRIDE;            // [128][136] bf16
    float* Cs = (float*)ldsb;                             // [64][132] f32 (reuse)

    int t = threadIdx.x;
    int n0 = blockIdx.x * 64;

    // stage x tile: 1024 uint2 (8 fp8 each), fp8->f32->relu->bf16 (exact)
    {
        const uint2* xg = (const uint2*)(x + (size_t)n0 * 32);
        int validq = min(64, N - n0) * 16;
#pragma unroll
        for (int i = 0; i < 4; i++) {
            int idx = t + i * 256;
            int row = idx >> 4, part = idx & 15;
            float f[8];
            if (idx < validq) {
                fp8x8_to_f8(xg[idx], f);
#pragma unroll
                for (int k = 0; k < 8; k++) f[k] = fmaxf(f[k], 0.f);
            } else {
#pragma unroll
                for (int k = 0; k < 8; k++) f[k] = 0.f;
            }
            bf16x8 v;
#pragma unroll
            for (int k = 0; k < 8; k++) v[k] = (short)f_to_bf_trunc(f[k]);
            *(bf16x8*)&xs[row * XS_STRIDE + part * 8] = v;
        }
    }
    // stage WT: 2048 uint4 (8 bf16 each)
    {
        const uint4* wg = (const uint4*)wt;
#pragma unroll
        for (int i = 0; i < 8; i++) {
            int idx = t + i * 256;
            int j = idx >> 4, part = idx & 15;
            uint4 v = wg[idx];
            *(uint4*)&wtl[j * WT_STRIDE + part * 8] = v;
        }
    }
    __syncthreads();

    int lane = t & 63, wv = t >> 6;
    int m = lane & 15, quad = lane >> 4;
    int rowbase = wv * 16;

    f32x4 acc[8];
#pragma unroll
    for (int c = 0; c < 8; c++) acc[c] = (f32x4){0.f, 0.f, 0.f, 0.f};

#pragma unroll
    for (int kt = 0; kt < 4; kt++) {
        bf16x8 a = *(bf16x8*)&xs[(rowbase + m) * XS_STRIDE + kt * 32 + quad * 8];
#pragma unroll
        for (int c = 0; c < 8; c++) {
            bf16x8 b = *(bf16x8*)&wtl[(c * 16 + m) * WT_STRIDE + kt * 32 + quad * 8];
            acc[c] = __builtin_amdgcn_mfma_f32_16x16x32_bf16(a, b, acc[c], 0, 0, 0);
        }
    }
    __syncthreads();   // done with xs/wtl; reuse as Cs

#pragma unroll
    for (int c = 0; c < 8; c++) {
#pragma unroll
        for (int r = 0; r < 4; r++) {
            Cs[(rowbase + quad * 4 + r) * C_STRIDE + c * 16 + m] = acc[c][r];
        }
    }
    __syncthreads();

    // epilogue: repack rows, scale by dis, quantize fp8
    int fq = t & 31, ng = t >> 5;
#pragma unroll
    for (int i = 0; i < 8; i++) {
        int lrow = ng * 8 + i;
        int n = n0 + lrow;
        if (n < N) {
            float4 v = *(const float4*)&Cs[lrow * C_STRIDE + 4 * fq];
            float dn = dis[n];
            h[(size_t)n * 32 + fq] = f4_to_fp8x4(v.x * dn, v.y * dn, v.z * dn, v.w * dn);
        }
    }
}

// agg[n] = b + dis[n] * (h'[n] + sum_src h'[src]); fp8 rows, fp32 accum
__global__ __launch_bounds__(256) void k_agg(const unsigned int* __restrict__ h,
                      const float* __restrict__ bias,
                      const float* __restrict__ dis, const int* __restrict__ offs,
                      const int* __restrict__ srcs, unsigned int* __restrict__ agg, int N) {
    int fq = threadIdx.x & 15, ng = threadIdx.x >> 4;
    int n = blockIdx.x * 16 + ng;
    if (n >= N) return;
    const uint2* hp = (const uint2*)h;
    float acc[8], tmp[8];
    fp8x8_to_f8(hp[(size_t)n * 16 + fq], acc);
    int e0 = offs[n], e1 = offs[n + 1];
    int e = e0;
    for (; e + 8 <= e1; e += 8) {
        int s0 = srcs[e + 0], s1 = srcs[e + 1], s2 = srcs[e + 2], s3 = srcs[e + 3];
        int s4 = srcs[e + 4], s5 = srcs[e + 5], s6 = srcs[e + 6], s7 = srcs[e + 7];
        uint2 r0 = hp[(size_t)s0 * 16 + fq];
        uint2 r1 = hp[(size_t)s1 * 16 + fq];
        uint2 r2 = hp[(size_t)s2 * 16 + fq];
        uint2 r3 = hp[(size_t)s3 * 16 + fq];
        uint2 r4 = hp[(size_t)s4 * 16 + fq];
        uint2 r5 = hp[(size_t)s5 * 16 + fq];
        uint2 r6 = hp[(size_t)s6 * 16 + fq];
        uint2 r7 = hp[(size_t)s7 * 16 + fq];
        fp8x8_to_f8(r0, tmp);
#pragma unroll
        for (int k = 0; k < 8; k++) acc[k] += tmp[k];
        fp8x8_to_f8(r1, tmp);
#pragma unroll
        for (int k = 0; k < 8; k++) acc[k] += tmp[k];
        fp8x8_to_f8(r2, tmp);
#pragma unroll
        for (int k = 0; k < 8; k++) acc[k] += tmp[k];
        fp8x8_to_f8(r3, tmp);
#pragma unroll
        for (int k = 0; k < 8; k++) acc[k] += tmp[k];
        fp8x8_to_f8(r4, tmp);
#pragma unroll
        for (int k = 0; k < 8; k++) acc[k] += tmp[k];
        fp8x8_to_f8(r5, tmp);
#pragma unroll
        for (int k = 0; k < 8; k++) acc[k] += tmp[k];
        fp8x8_to_f8(r6, tmp);
#pragma unroll
        for (int k = 0; k < 8; k++) acc[k] += tmp[k];
        fp8x8_to_f8(r7, tmp);
#pragma unroll
        for (int k = 0; k < 8; k++) acc[k] += tmp[k];
    }
    for (; e < e1; ++e) {
        int s = srcs[e];
        fp8x8_to_f8(hp[(size_t)s * 16 + fq], tmp);
#pragma unroll
        for (int k = 0; k < 8; k++) acc[k] += tmp[k];
    }
    float dn = dis[n];
    const float4 bv0 = *(const float4*)&bias[8 * fq];
    const float4 bv1 = *(const float4*)&bias[8 * fq + 4];
    unsigned int lo = f4_to_fp8x4(bv0.x + dn * acc[0], bv0.y + dn * acc[1],
                                  bv0.z + dn * acc[2], bv0.w + dn * acc[3]);
    unsigned int hi = f4_to_fp8x4(bv1.x + dn * acc[4], bv1.y + dn * acc[5],
                                  bv1.z + dn * acc[6], bv1.w + dn * acc[7]);
    uint2 outv = make_uint2(lo, hi);
    *(uint2*)&agg[(size_t)n * 32 + 2 * fq] = outv;
}

// ---- Pool + head ----------------------------------------------------------

__global__ void k_pool(const unsigned char* __restrict__ x, const int* __restrict__ batch,
                       float* __restrict__ pooled, int N) {
    int g = blockIdx.x >> 3, c = blockIdx.x & 7;
    int start = lower_bound_i(batch, N, g);
    int end   = lower_bound_i(batch, N, g + 1);
    int len = end - start;
    int cb = start + (int)((long)len * c / 8);
    int ce = start + (int)((long)len * (c + 1) / 8);
    int f = threadIdx.x & 127, half = threadIdx.x >> 7;
    float acc = 0.f;
    for (int n = cb + half; n < ce; n += 2) {
        int b = x[(size_t)n * 128 + f];
        vf2 v = __builtin_amdgcn_cvt_pk_f32_fp8(b, false);
        acc += fmaxf(v.x, 0.f);
    }
    __shared__ float sh[128];
    if (half == 1) sh[f] = acc;
    __syncthreads();
    if (half == 0) atomicAdd(&pooled[g * 128 + f], acc + sh[f]);
}

__global__ void k_head(const float* __restrict__ pooled, const int* __restrict__ batch,
                       const float* __restrict__ linW, const float* __restrict__ linb,
                       float* __restrict__ out, int N) {
    int g = threadIdx.x;
    if (g >= 64) return;
    int start = lower_bound_i(batch, N, g);
    int end   = lower_bound_i(batch, N, g + 1);
    float cnt = fmaxf((float)(end - start), 1.0f);
    float logits[8];
#pragma unroll
    for (int j = 0; j < 8; j++) logits[j] = linb[j];
    for (int f = 0; f < 128; f++) {
        float p = pooled[g * 128 + f] / cnt;
#pragma unroll
        for (int j = 0; j < 8; j++) logits[j] += p * linW[f * 8 + j];
    }
    float m = logits[0];
#pragma unroll
    for (int j = 1; j < 8; j++) m = fmaxf(m, logits[j]);
    float s = 0.f;
    float e[8];
#pragma unroll
    for (int j = 0; j < 8; j++) { e[j] = expf(logits[j] - m); s += e[j]; }
#pragma unroll
    for (int j = 0; j < 8; j++) out[g * 8 + j] = e[j] / s;
}

// ---- Launch ---------------------------------------------------------------

extern "C" void kernel_launch(void* const* d_in, const int* in_sizes, int n_in,
                              void* d_out, int out_size, void* d_ws, size_t ws_size,
                              hipStream_t stream) {
    const float* an   = (const float*)d_in[0];
    const float* pos  = (const float*)d_in[1];
    const float* W0   = (const float*)d_in[2];
    const float* b0   = (const float*)d_in[3];
    const float* W1   = (const float*)d_in[4];
    const float* b1   = (const float*)d_in[5];
    const float* W2   = (const float*)d_in[6];
    const float* b2   = (const float*)d_in[7];
    const float* linW = (const float*)d_in[8];
    const float* linb = (const float*)d_in[9];
    const int*   ei   = (const int*)d_in[10];
    const int*   batch= (const int*)d_in[11];

    int N = in_sizes[0];
    int E = in_sizes[10] / 2;
    const int* esrc = ei;
    const int* edst = ei + E;
    int nb = (N + (1 << BSHIFT) - 1) >> BSHIFT;   // 196 for N=100000

    char* p = (char*)d_ws;
    auto carve = [&](size_t bytes) -> void* {
        void* r = (void*)p;
        p += (bytes + 255) & ~(size_t)255;
        return r;
    };
    unsigned int* bufA = (unsigned int*)carve((size_t)N * 128);   // fp8 rows
    unsigned int* bufB = (unsigned int*)carve((size_t)N * 128);
    float* dis    = (float*)carve((size_t)N * 4);
    int*   offs   = (int*)  carve((size_t)(N + 1) * 4);
    int*   srcs   = (int*)  carve((size_t)E * 4);
    int*   pairs  = (int*)  carve((size_t)E * 4);
    int*   gcounts= (int*)  carve((size_t)NB * NBLK * 4);
    unsigned short* wt1 = (unsigned short*)carve(128 * 128 * 2); // bf16 W1^T
    unsigned short* wt2 = (unsigned short*)carve(128 * 128 * 2); // bf16 W2^T
    float* pooled = (float*)carve(64 * 128 * 4);

    hipMemsetAsync(pooled, 0, 64 * 128 * 4, stream);

    // CSR build: deterministic radix partition + per-bucket LDS build
    k_cnt     <<<NBLK, WG, 0, stream>>>(edst, E, gcounts);
    k_scan_mat<<<1, 1024, 0, stream>>>(gcounts);
    k_scat    <<<NBLK, WG, 0, stream>>>(esrc, edst, E, gcounts, pairs);
    k_build   <<<nb, WG, 0, stream>>>(pairs, gcounts, N, E, offs, srcs, dis);

    // W transposes (bf16)
    k_wt<<<64, WG, 0, stream>>>(W1, wt1);
    k_wt<<<64, WG, 0, stream>>>(W2, wt2);

    // layers
    k_l0  <<<((size_t)N * 32 + WG - 1) / WG, WG, 0, stream>>>(an, pos, W0, dis, bufA, N);
    k_agg <<<(N + 15) / 16, WG, 0, stream>>>(bufA, b0, dis, offs, srcs, bufB, N);
    k_gemm<<<(N + 63) / 64, WG, 0, stream>>>(bufB, wt1, dis, bufA, N);
    k_agg <<<(N + 15) / 16, WG, 0, stream>>>(bufA, b1, dis, offs, srcs, bufB, N);
    k_gemm<<<(N + 63) / 64, WG, 0, stream>>>(bufB, wt2, dis, bufA, N);
    k_agg <<<(N + 15) / 16, WG, 0, stream>>>(bufA, b2, dis, offs, srcs, bufB, N);

    // pool + head
    k_pool<<<64 * 8, WG, 0, stream>>>((const unsigned char*)bufB, batch, pooled, N);
    k_head<<<1, 64, 0, stream>>>(pooled, batch, linW, linb, (float*)d_out, N);
}

// Round 7
// 346.751 us; speedup vs baseline: 3.0265x; 1.1290x over previous
//
#include <hip/hip_runtime.h>
#include <math.h>

#define WG 256
#define NB 256             // radix buckets (node-range 512 each -> N <= 131072)
#define BSHIFT 9
#define NBLK 512           // partition blocks

typedef float vf2 __attribute__((ext_vector_type(2)));
typedef short bf16x8 __attribute__((ext_vector_type(8)));
typedef float f32x4 __attribute__((ext_vector_type(4)));

#define XS_STRIDE 136      // ushort stride, 16B-aligned rows + conflict pad
#define WT_STRIDE 136
#define C_STRIDE 132       // float stride, 16B-aligned

__device__ __forceinline__ int lower_bound_i(const int* __restrict__ a, int n, int key) {
    int lo = 0, hi = n;
    while (lo < hi) { int mid = (lo + hi) >> 1; if (a[mid] < key) lo = mid + 1; else hi = mid; }
    return lo;
}

// ---- fp8 (OCP e4m3) helpers ------------------------------------------------
__device__ __forceinline__ void fp8x8_to_f8(uint2 raw, float* f) {
    vf2 a = __builtin_amdgcn_cvt_pk_f32_fp8((int)raw.x, false);
    vf2 b = __builtin_amdgcn_cvt_pk_f32_fp8((int)raw.x, true);
    vf2 c = __builtin_amdgcn_cvt_pk_f32_fp8((int)raw.y, false);
    vf2 d = __builtin_amdgcn_cvt_pk_f32_fp8((int)raw.y, true);
    f[0]=a.x; f[1]=a.y; f[2]=b.x; f[3]=b.y; f[4]=c.x; f[5]=c.y; f[6]=d.x; f[7]=d.y;
}
__device__ __forceinline__ unsigned int f4_to_fp8x4(float x, float y, float z, float w) {
    int v = __builtin_amdgcn_cvt_pk_fp8_f32(x, y, 0, false);
    v = __builtin_amdgcn_cvt_pk_fp8_f32(z, w, v, true);
    return (unsigned int)v;
}
__device__ __forceinline__ unsigned short f_to_bf_trunc(float f) {
    return (unsigned short)(__float_as_uint(f) >> 16);
}
__device__ __forceinline__ unsigned short f_to_bf_rne(float f) {
    unsigned int u = __float_as_uint(f);
    u += 0x7FFFu + ((u >> 16) & 1u);
    return (unsigned short)(u >> 16);
}

// ---- CSR build: deterministic radix partition (no global atomics) ----------

__global__ __launch_bounds__(256) void k_cnt(const int* __restrict__ edst, int E,
                                             int* __restrict__ gcounts) {
    __shared__ int hist[NB];
    int t = threadIdx.x, blk = blockIdx.x;
    if (t < NB) hist[t] = 0;
    __syncthreads();
    int chunk = (E + NBLK - 1) / NBLK;
    int e0 = blk * chunk, e1 = min(E, e0 + chunk);
    for (int e = e0 + t; e < e1; e += 256) atomicAdd(&hist[edst[e] >> BSHIFT], 1);
    __syncthreads();
    if (t < NB) gcounts[t * NBLK + blk] = hist[t];
}

// hierarchical scan A: 128 blocks x 1024 entries; in-place block-local
// exclusive prefix + block totals
__global__ __launch_bounds__(256) void k_scanA(int* __restrict__ gcounts,
                                               int* __restrict__ bsum) {
    __shared__ int wtot[4];
    int t = threadIdx.x;
    int base = blockIdx.x * 1024 + t * 4;
    int4 v = *(const int4*)&gcounts[base];
    int s = v.x + v.y + v.z + v.w;
    int lane = t & 63, wid = t >> 6;
    int x = s;
#pragma unroll
    for (int d = 1; d < 64; d <<= 1) { int y = __shfl_up(x, d); if (lane >= d) x += y; }
    if (lane == 63) wtot[wid] = x;
    __syncthreads();
    int woff = 0;
    for (int w = 0; w < wid; w++) woff += wtot[w];
    int excl = woff + x - s;
    int4 o;
    o.x = excl; o.y = excl + v.x; o.z = o.y + v.y; o.w = o.z + v.z;
    *(int4*)&gcounts[base] = o;
    if (t == 255) bsum[blockIdx.x] = woff + x;
}

// hierarchical scan B: exclusive scan of the 128 block totals (in place)
__global__ void k_scanB(int* __restrict__ bsum) {
    __shared__ int sh[128];
    int t = threadIdx.x;
    int v = bsum[t];
    sh[t] = v;
    __syncthreads();
    for (int d = 1; d < 128; d <<= 1) {
        int a = (t >= d) ? sh[t - d] : 0;
        __syncthreads();
        sh[t] += a;
        __syncthreads();
    }
    bsum[t] = sh[t] - v;
}

// scatter edges packed as (src << 9) | (dst & 511)
__global__ __launch_bounds__(256) void k_scat(const int* __restrict__ esrc,
        const int* __restrict__ edst, int E,
        const int* __restrict__ gcounts, const int* __restrict__ bsum,
        int* __restrict__ pairs) {
    __shared__ int cur[NB];
    int t = threadIdx.x, blk = blockIdx.x;
    if (t < NB) {
        int idx = t * NBLK + blk;
        cur[t] = gcounts[idx] + bsum[idx >> 10];
    }
    __syncthreads();
    int chunk = (E + NBLK - 1) / NBLK;
    int e0 = blk * chunk, e1 = min(E, e0 + chunk);
    for (int e = e0 + t; e < e1; e += 256) {
        int d = edst[e], s = esrc[e];
        int pos = atomicAdd(&cur[d >> BSHIFT], 1);
        pairs[pos] = (s << BSHIFT) | (d & ((1 << BSHIFT) - 1));
    }
}

__global__ __launch_bounds__(256) void k_build(const int* __restrict__ pairs,
        const int* __restrict__ gcounts, const int* __restrict__ bsum, int N, int E,
        int* __restrict__ offs, int* __restrict__ srcs, float* __restrict__ dis) {
    __shared__ int cnt[512];
    __shared__ int wtot[4];
    int b = blockIdx.x, t = threadIdx.x;
    int n0 = b << BSHIFT;
    cnt[2 * t] = 0; cnt[2 * t + 1] = 0;
    __syncthreads();
    int i0 = b * NBLK, i1 = (b + 1) * NBLK;     // b+1 <= nb < NB so i1 in range
    int bs = gcounts[i0] + bsum[i0 >> 10];
    int be = gcounts[i1] + bsum[i1 >> 10];
    int m = be - bs;
    const int* pb = &pairs[bs];
    for (int i = t; i < m; i += 256) {
        int p = pb[i];
        atomicAdd(&cnt[p & 511], 1);
    }
    __syncthreads();
    int v0 = cnt[2 * t], v1 = cnt[2 * t + 1];
    int ts = v0 + v1;
    int lane = t & 63, wid = t >> 6;
    int x = ts;
    #pragma unroll
    for (int d = 1; d < 64; d <<= 1) { int y = __shfl_up(x, d); if (lane >= d) x += y; }
    if (lane == 63) wtot[wid] = x;
    __syncthreads();
    int woff = 0;
    for (int w = 0; w < wid; w++) woff += wtot[w];
    int excl = woff + x - ts;
    int o0 = excl, o1 = excl + v0;
    cnt[2 * t] = o0; cnt[2 * t + 1] = o1;
    int n = n0 + 2 * t;
    if (n + 0 < N) { offs[n + 0] = bs + o0; dis[n + 0] = rsqrtf((float)(v0 + 1)); }
    if (n + 1 < N) { offs[n + 1] = bs + o1; dis[n + 1] = rsqrtf((float)(v1 + 1)); }
    if (b == gridDim.x - 1 && t == 255) offs[N] = E;
    __syncthreads();
    for (int i = t; i < m; i += 256) {
        int p = pb[i];
        int pos = atomicAdd(&cnt[p & 511], 1);
        srcs[bs + pos] = p >> BSHIFT;
    }
}

// ---- W transpose to bf16: WT[j][k] = bf16(W[k][j]) -------------------------
__global__ __launch_bounds__(256) void k_wt(const float* __restrict__ W,
                                            unsigned short* __restrict__ wt) {
    int idx = blockIdx.x * 256 + threadIdx.x;   // 64 blocks -> 16384
    int k = idx >> 7, j = idx & 127;
    float v = W[k * 128 + j];
    wt[j * 128 + k] = f_to_bf_rne(v);
}

// ---- Layer kernels --------------------------------------------------------

// layer0: h'[n][f] = (x0[n] @ W0)[f] * dis[n], stored fp8
__global__ void k_l0(const float* __restrict__ an, const float* __restrict__ pos,
                     const float* __restrict__ W0, const float* __restrict__ dis,
                     unsigned int* __restrict__ h, int N) {
    int idx = blockIdx.x * blockDim.x + threadIdx.x;
    int n = idx >> 5, fq = idx & 31;
    if (n >= N) return;
    float a = an[n];
    float px = pos[n * 3 + 0], py = pos[n * 3 + 1], pz = pos[n * 3 + 2];
    float dn = dis[n];
    const float4 w0 = *(const float4*)&W0[0 * 128 + 4 * fq];
    const float4 w1 = *(const float4*)&W0[1 * 128 + 4 * fq];
    const float4 w2 = *(const float4*)&W0[2 * 128 + 4 * fq];
    const float4 w3 = *(const float4*)&W0[3 * 128 + 4 * fq];
    float4 r;
    r.x = (a * w0.x + px * w1.x + py * w2.x + pz * w3.x) * dn;
    r.y = (a * w0.y + px * w1.y + py * w2.y + pz * w3.y) * dn;
    r.z = (a * w0.z + px * w1.z + py * w2.z + pz * w3.z) * dn;
    r.w = (a * w0.w + px * w1.w + py * w2.w + pz * w3.w) * dn;
    h[(size_t)n * 32 + fq] = f4_to_fp8x4(r.x, r.y, r.z, r.w);
}

// MFMA GEMM: h'[n][f] = (relu(x[n]) @ W)[f] * dis[n]
__global__ __launch_bounds__(256) void k_gemm(const unsigned int* __restrict__ x,
                                              const unsigned short* __restrict__ wt,
                                              const float* __restrict__ dis,
                                              unsigned int* __restrict__ h, int N) {
    __shared__ __align__(16) char ldsb[(64 * XS_STRIDE + 128 * WT_STRIDE) * 2];
    unsigned short* xs  = (unsigned short*)ldsb;          // [64][136] bf16
    unsigned short* wtl = xs + 64 * XS_STRIDE;            // [128][136] bf16
    float* Cs = (float*)ldsb;                             // [64][132] f32 (reuse)

    int t = threadIdx.x;
    int n0 = blockIdx.x * 64;

    {
        const uint2* xg = (const uint2*)(x + (size_t)n0 * 32);
        int validq = min(64, N - n0) * 16;
#pragma unroll
        for (int i = 0; i < 4; i++) {
            int idx = t + i * 256;
            int row = idx >> 4, part = idx & 15;
            float f[8];
            if (idx < validq) {
                fp8x8_to_f8(xg[idx], f);
#pragma unroll
                for (int k = 0; k < 8; k++) f[k] = fmaxf(f[k], 0.f);
            } else {
#pragma unroll
                for (int k = 0; k < 8; k++) f[k] = 0.f;
            }
            bf16x8 v;
#pragma unroll
            for (int k = 0; k < 8; k++) v[k] = (short)f_to_bf_trunc(f[k]);
            *(bf16x8*)&xs[row * XS_STRIDE + part * 8] = v;
        }
    }
    {
        const uint4* wg = (const uint4*)wt;
#pragma unroll
        for (int i = 0; i < 8; i++) {
            int idx = t + i * 256;
            int j = idx >> 4, part = idx & 15;
            uint4 v = wg[idx];
            *(uint4*)&wtl[j * WT_STRIDE + part * 8] = v;
        }
    }
    __syncthreads();

    int lane = t & 63, wv = t >> 6;
    int m = lane & 15, quad = lane >> 4;
    int rowbase = wv * 16;

    f32x4 acc[8];
#pragma unroll
    for (int c = 0; c < 8; c++) acc[c] = (f32x4){0.f, 0.f, 0.f, 0.f};

#pragma unroll
    for (int kt = 0; kt < 4; kt++) {
        bf16x8 a = *(bf16x8*)&xs[(rowbase + m) * XS_STRIDE + kt * 32 + quad * 8];
#pragma unroll
        for (int c = 0; c < 8; c++) {
            bf16x8 b = *(bf16x8*)&wtl[(c * 16 + m) * WT_STRIDE + kt * 32 + quad * 8];
            acc[c] = __builtin_amdgcn_mfma_f32_16x16x32_bf16(a, b, acc[c], 0, 0, 0);
        }
    }
    __syncthreads();

#pragma unroll
    for (int c = 0; c < 8; c++) {
#pragma unroll
        for (int r = 0; r < 4; r++) {
            Cs[(rowbase + quad * 4 + r) * C_STRIDE + c * 16 + m] = acc[c][r];
        }
    }
    __syncthreads();

    int fq = t & 31, ng = t >> 5;
#pragma unroll
    for (int i = 0; i < 8; i++) {
        int lrow = ng * 8 + i;
        int n = n0 + lrow;
        if (n < N) {
            float4 v = *(const float4*)&Cs[lrow * C_STRIDE + 4 * fq];
            float dn = dis[n];
            h[(size_t)n * 32 + fq] = f4_to_fp8x4(v.x * dn, v.y * dn, v.z * dn, v.w * dn);
        }
    }
}

// agg[n] = b + dis[n] * (h'[n] + sum_src h'[src]); fp8 rows, fp32 accum
__global__ __launch_bounds__(256) void k_agg(const unsigned int* __restrict__ h,
                      const float* __restrict__ bias,
                      const float* __restrict__ dis, const int* __restrict__ offs,
                      const int* __restrict__ srcs, unsigned int* __restrict__ agg, int N) {
    int fq = threadIdx.x & 15, ng = threadIdx.x >> 4;
    int n = blockIdx.x * 16 + ng;
    if (n >= N) return;
    const uint2* hp = (const uint2*)h;
    float acc[8], tmp[8];
    fp8x8_to_f8(hp[(size_t)n * 16 + fq], acc);
    int e0 = offs[n], e1 = offs[n + 1];
    int e = e0;
    for (; e + 8 <= e1; e += 8) {
        int s0 = srcs[e + 0], s1 = srcs[e + 1], s2 = srcs[e + 2], s3 = srcs[e + 3];
        int s4 = srcs[e + 4], s5 = srcs[e + 5], s6 = srcs[e + 6], s7 = srcs[e + 7];
        uint2 r0 = hp[(size_t)s0 * 16 + fq];
        uint2 r1 = hp[(size_t)s1 * 16 + fq];
        uint2 r2 = hp[(size_t)s2 * 16 + fq];
        uint2 r3 = hp[(size_t)s3 * 16 + fq];
        uint2 r4 = hp[(size_t)s4 * 16 + fq];
        uint2 r5 = hp[(size_t)s5 * 16 + fq];
        uint2 r6 = hp[(size_t)s6 * 16 + fq];
        uint2 r7 = hp[(size_t)s7 * 16 + fq];
        fp8x8_to_f8(r0, tmp);
#pragma unroll
        for (int k = 0; k < 8; k++) acc[k] += tmp[k];
        fp8x8_to_f8(r1, tmp);
#pragma unroll
        for (int k = 0; k < 8; k++) acc[k] += tmp[k];
        fp8x8_to_f8(r2, tmp);
#pragma unroll
        for (int k = 0; k < 8; k++) acc[k] += tmp[k];
        fp8x8_to_f8(r3, tmp);
#pragma unroll
        for (int k = 0; k < 8; k++) acc[k] += tmp[k];
        fp8x8_to_f8(r4, tmp);
#pragma unroll
        for (int k = 0; k < 8; k++) acc[k] += tmp[k];
        fp8x8_to_f8(r5, tmp);
#pragma unroll
        for (int k = 0; k < 8; k++) acc[k] += tmp[k];
        fp8x8_to_f8(r6, tmp);
#pragma unroll
        for (int k = 0; k < 8; k++) acc[k] += tmp[k];
        fp8x8_to_f8(r7, tmp);
#pragma unroll
        for (int k = 0; k < 8; k++) acc[k] += tmp[k];
    }
    for (; e < e1; ++e) {
        int s = srcs[e];
        fp8x8_to_f8(hp[(size_t)s * 16 + fq], tmp);
#pragma unroll
        for (int k = 0; k < 8; k++) acc[k] += tmp[k];
    }
    float dn = dis[n];
    const float4 bv0 = *(const float4*)&bias[8 * fq];
    const float4 bv1 = *(const float4*)&bias[8 * fq + 4];
    unsigned int lo = f4_to_fp8x4(bv0.x + dn * acc[0], bv0.y + dn * acc[1],
                                  bv0.z + dn * acc[2], bv0.w + dn * acc[3]);
    unsigned int hi = f4_to_fp8x4(bv1.x + dn * acc[4], bv1.y + dn * acc[5],
                                  bv1.z + dn * acc[6], bv1.w + dn * acc[7]);
    uint2 outv = make_uint2(lo, hi);
    *(uint2*)&agg[(size_t)n * 32 + 2 * fq] = outv;
}

// ---- Pool + head ----------------------------------------------------------

__global__ void k_pool(const unsigned char* __restrict__ x, const int* __restrict__ batch,
                       float* __restrict__ pooled, int N) {
    int g = blockIdx.x >> 3, c = blockIdx.x & 7;
    int start = lower_bound_i(batch, N, g);
    int end   = lower_bound_i(batch, N, g + 1);
    int len = end - start;
    int cb = start + (int)((long)len * c / 8);
    int ce = start + (int)((long)len * (c + 1) / 8);
    int f = threadIdx.x & 127, half = threadIdx.x >> 7;
    float acc = 0.f;
    for (int n = cb + half; n < ce; n += 2) {
        int b = x[(size_t)n * 128 + f];
        vf2 v = __builtin_amdgcn_cvt_pk_f32_fp8(b, false);
        acc += fmaxf(v.x, 0.f);
    }
    __shared__ float sh[128];
    if (half == 1) sh[f] = acc;
    __syncthreads();
    if (half == 0) atomicAdd(&pooled[g * 128 + f], acc + sh[f]);
}

__global__ void k_head(const float* __restrict__ pooled, const int* __restrict__ batch,
                       const float* __restrict__ linW, const float* __restrict__ linb,
                       float* __restrict__ out, int N) {
    int g = threadIdx.x;
    if (g >= 64) return;
    int start = lower_bound_i(batch, N, g);
    int end   = lower_bound_i(batch, N, g + 1);
    float cnt = fmaxf((float)(end - start), 1.0f);
    float logits[8];
#pragma unroll
    for (int j = 0; j < 8; j++) logits[j] = linb[j];
    for (int f = 0; f < 128; f++) {
        float p = pooled[g * 128 + f] / cnt;
#pragma unroll
        for (int j = 0; j < 8; j++) logits[j] += p * linW[f * 8 + j];
    }
    float m = logits[0];
#pragma unroll
    for (int j = 1; j < 8; j++) m = fmaxf(m, logits[j]);
    float s = 0.f;
    float e[8];
#pragma unroll
    for (int j = 0; j < 8; j++) { e[j] = expf(logits[j] - m); s += e[j]; }
#pragma unroll
    for (int j = 0; j < 8; j++) out[g * 8 + j] = e[j] / s;
}

// ---- Launch ---------------------------------------------------------------

extern "C" void kernel_launch(void* const* d_in, const int* in_sizes, int n_in,
                              void* d_out, int out_size, void* d_ws, size_t ws_size,
                              hipStream_t stream) {
    const float* an   = (const float*)d_in[0];
    const float* pos  = (const float*)d_in[1];
    const float* W0   = (const float*)d_in[2];
    const float* b0   = (const float*)d_in[3];
    const float* W1   = (const float*)d_in[4];
    const float* b1   = (const float*)d_in[5];
    const float* W2   = (const float*)d_in[6];
    const float* b2   = (const float*)d_in[7];
    const float* linW = (const float*)d_in[8];
    const float* linb = (const float*)d_in[9];
    const int*   ei   = (const int*)d_in[10];
    const int*   batch= (const int*)d_in[11];

    int N = in_sizes[0];
    int E = in_sizes[10] / 2;
    const int* esrc = ei;
    const int* edst = ei + E;
    int nb = (N + (1 << BSHIFT) - 1) >> BSHIFT;   // 196 for N=100000

    char* p = (char*)d_ws;
    auto carve = [&](size_t bytes) -> void* {
        void* r = (void*)p;
        p += (bytes + 255) & ~(size_t)255;
        return r;
    };
    unsigned int* bufA = (unsigned int*)carve((size_t)N * 128);   // fp8 rows
    unsigned int* bufB = (unsigned int*)carve((size_t)N * 128);
    float* dis    = (float*)carve((size_t)N * 4);
    int*   offs   = (int*)  carve((size_t)(N + 1) * 4);
    int*   srcs   = (int*)  carve((size_t)E * 4);
    int*   pairs  = (int*)  carve((size_t)E * 4);
    int*   gcounts= (int*)  carve((size_t)NB * NBLK * 4);
    int*   bsum   = (int*)  carve(128 * 4);
    unsigned short* wt1 = (unsigned short*)carve(128 * 128 * 2);
    unsigned short* wt2 = (unsigned short*)carve(128 * 128 * 2);
    float* pooled = (float*)carve(64 * 128 * 4);

    hipMemsetAsync(pooled, 0, 64 * 128 * 4, stream);

    // CSR build: deterministic radix partition + hierarchical scan
    k_cnt  <<<NBLK, WG, 0, stream>>>(edst, E, gcounts);
    k_scanA<<<128, WG, 0, stream>>>(gcounts, bsum);
    k_scanB<<<1, 128, 0, stream>>>(bsum);
    k_scat <<<NBLK, WG, 0, stream>>>(esrc, edst, E, gcounts, bsum, pairs);
    k_build<<<nb, WG, 0, stream>>>(pairs, gcounts, bsum, N, E, offs, srcs, dis);

    // W transposes (bf16)
    k_wt<<<64, WG, 0, stream>>>(W1, wt1);
    k_wt<<<64, WG, 0, stream>>>(W2, wt2);

    // layers
    k_l0  <<<((size_t)N * 32 + WG - 1) / WG, WG, 0, stream>>>(an, pos, W0, dis, bufA, N);
    k_agg <<<(N + 15) / 16, WG, 0, stream>>>(bufA, b0, dis, offs, srcs, bufB, N);
    k_gemm<<<(N + 63) / 64, WG, 0, stream>>>(bufB, wt1, dis, bufA, N);
    k_agg <<<(N + 15) / 16, WG, 0, stream>>>(bufA, b1, dis, offs, srcs, bufB, N);
    k_gemm<<<(N + 63) / 64, WG, 0, stream>>>(bufB, wt2, dis, bufA, N);
    k_agg <<<(N + 15) / 16, WG, 0, stream>>>(bufA, b2, dis, offs, srcs, bufB, N);

    // pool + head
    k_pool<<<64 * 8, WG, 0, stream>>>((const unsigned char*)bufB, batch, pooled, N);
    k_head<<<1, 64, 0, stream>>>(pooled, batch, linW, linb, (float*)d_out, N);
}

// Round 8
// 342.608 us; speedup vs baseline: 3.0631x; 1.0121x over previous
//
#include <hip/hip_runtime.h>
#include <math.h>

#define WG 256
#define NB 256             // radix buckets (node-range 512 each -> N <= 131072)
#define BSHIFT 9
#define NBLK 256           // partition blocks

typedef float vf2 __attribute__((ext_vector_type(2)));
typedef short bf16x8 __attribute__((ext_vector_type(8)));
typedef float f32x4 __attribute__((ext_vector_type(4)));

#define XS_STRIDE 136      // ushort stride, 16B-aligned rows + conflict pad
#define WT_STRIDE 136
#define C_STRIDE 132       // float stride, 16B-aligned

__device__ __forceinline__ int lower_bound_i(const int* __restrict__ a, int n, int key) {
    int lo = 0, hi = n;
    while (lo < hi) { int mid = (lo + hi) >> 1; if (a[mid] < key) lo = mid + 1; else hi = mid; }
    return lo;
}

// ---- fp8 (OCP e4m3) helpers ------------------------------------------------
__device__ __forceinline__ void fp8x8_to_f8(uint2 raw, float* f) {
    vf2 a = __builtin_amdgcn_cvt_pk_f32_fp8((int)raw.x, false);
    vf2 b = __builtin_amdgcn_cvt_pk_f32_fp8((int)raw.x, true);
    vf2 c = __builtin_amdgcn_cvt_pk_f32_fp8((int)raw.y, false);
    vf2 d = __builtin_amdgcn_cvt_pk_f32_fp8((int)raw.y, true);
    f[0]=a.x; f[1]=a.y; f[2]=b.x; f[3]=b.y; f[4]=c.x; f[5]=c.y; f[6]=d.x; f[7]=d.y;
}
__device__ __forceinline__ void fp8x16_to_f(uint4 raw, float* f) {
    uint2 lo, hi;
    lo.x = raw.x; lo.y = raw.y; hi.x = raw.z; hi.y = raw.w;
    fp8x8_to_f8(lo, f);
    fp8x8_to_f8(hi, f + 8);
}
__device__ __forceinline__ unsigned int f4_to_fp8x4(float x, float y, float z, float w) {
    int v = __builtin_amdgcn_cvt_pk_fp8_f32(x, y, 0, false);
    v = __builtin_amdgcn_cvt_pk_fp8_f32(z, w, v, true);
    return (unsigned int)v;
}
__device__ __forceinline__ unsigned short f_to_bf_trunc(float f) {
    return (unsigned short)(__float_as_uint(f) >> 16);
}
__device__ __forceinline__ unsigned short f_to_bf_rne(float f) {
    unsigned int u = __float_as_uint(f);
    u += 0x7FFFu + ((u >> 16) & 1u);
    return (unsigned short)(u >> 16);
}

// ---- CSR build: deterministic radix partition (no global atomics) ----------

__global__ __launch_bounds__(256) void k_cnt(const int* __restrict__ edst, int E,
                                             int* __restrict__ gcounts) {
    __shared__ int hist[NB];
    int t = threadIdx.x, blk = blockIdx.x;
    if (t < NB) hist[t] = 0;
    __syncthreads();
    int chunk = (E + NBLK - 1) / NBLK;
    int e0 = blk * chunk, e1 = min(E, e0 + chunk);
    for (int e = e0 + t; e < e1; e += 256) atomicAdd(&hist[edst[e] >> BSHIFT], 1);
    __syncthreads();
    if (t < NB) gcounts[t * NBLK + blk] = hist[t];
}

// hierarchical scan A: 64 blocks x 1024 entries; in-place block-local
// exclusive prefix + block totals
__global__ __launch_bounds__(256) void k_scanA(int* __restrict__ gcounts,
                                               int* __restrict__ bsum) {
    __shared__ int wtot[4];
    int t = threadIdx.x;
    int base = blockIdx.x * 1024 + t * 4;
    int4 v = *(const int4*)&gcounts[base];
    int s = v.x + v.y + v.z + v.w;
    int lane = t & 63, wid = t >> 6;
    int x = s;
#pragma unroll
    for (int d = 1; d < 64; d <<= 1) { int y = __shfl_up(x, d); if (lane >= d) x += y; }
    if (lane == 63) wtot[wid] = x;
    __syncthreads();
    int woff = 0;
    for (int w = 0; w < wid; w++) woff += wtot[w];
    int excl = woff + x - s;
    int4 o;
    o.x = excl; o.y = excl + v.x; o.z = o.y + v.y; o.w = o.z + v.z;
    *(int4*)&gcounts[base] = o;
    if (t == 255) bsum[blockIdx.x] = woff + x;
}

// hierarchical scan B: exclusive scan of 64 block totals (single wave)
__global__ void k_scanB(int* __restrict__ bsum) {
    int t = threadIdx.x;   // 64 threads
    int v = bsum[t];
    int x = v;
#pragma unroll
    for (int d = 1; d < 64; d <<= 1) { int y = __shfl_up(x, d); if (t >= d) x += y; }
    bsum[t] = x - v;
}

// scatter edges packed as (src << 9) | (dst & 511)
__global__ __launch_bounds__(256) void k_scat(const int* __restrict__ esrc,
        const int* __restrict__ edst, int E,
        const int* __restrict__ gcounts, const int* __restrict__ bsum,
        int* __restrict__ pairs) {
    __shared__ int cur[NB];
    int t = threadIdx.x, blk = blockIdx.x;
    if (t < NB) {
        int idx = t * NBLK + blk;
        cur[t] = gcounts[idx] + bsum[idx >> 10];
    }
    __syncthreads();
    int chunk = (E + NBLK - 1) / NBLK;
    int e0 = blk * chunk, e1 = min(E, e0 + chunk);
    for (int e = e0 + t; e < e1; e += 256) {
        int d = edst[e], s = esrc[e];
        int pos = atomicAdd(&cur[d >> BSHIFT], 1);
        pairs[pos] = (s << BSHIFT) | (d & ((1 << BSHIFT) - 1));
    }
}

__global__ __launch_bounds__(256) void k_build(const int* __restrict__ pairs,
        const int* __restrict__ gcounts, const int* __restrict__ bsum, int N, int E,
        int* __restrict__ offs, int* __restrict__ srcs, float* __restrict__ dis) {
    __shared__ int cnt[512];
    __shared__ int wtot[4];
    int b = blockIdx.x, t = threadIdx.x;
    int n0 = b << BSHIFT;
    cnt[2 * t] = 0; cnt[2 * t + 1] = 0;
    __syncthreads();
    int i0 = b * NBLK, i1 = (b + 1) * NBLK;     // b+1 <= nb < NB so i1 in range
    int bs = gcounts[i0] + bsum[i0 >> 10];
    int be = gcounts[i1] + bsum[i1 >> 10];
    int m = be - bs;
    const int* pb = &pairs[bs];
    for (int i = t; i < m; i += 256) {
        int p = pb[i];
        atomicAdd(&cnt[p & 511], 1);
    }
    __syncthreads();
    int v0 = cnt[2 * t], v1 = cnt[2 * t + 1];
    int ts = v0 + v1;
    int lane = t & 63, wid = t >> 6;
    int x = ts;
    #pragma unroll
    for (int d = 1; d < 64; d <<= 1) { int y = __shfl_up(x, d); if (lane >= d) x += y; }
    if (lane == 63) wtot[wid] = x;
    __syncthreads();
    int woff = 0;
    for (int w = 0; w < wid; w++) woff += wtot[w];
    int excl = woff + x - ts;
    int o0 = excl, o1 = excl + v0;
    cnt[2 * t] = o0; cnt[2 * t + 1] = o1;
    int n = n0 + 2 * t;
    if (n + 0 < N) { offs[n + 0] = bs + o0; dis[n + 0] = rsqrtf((float)(v0 + 1)); }
    if (n + 1 < N) { offs[n + 1] = bs + o1; dis[n + 1] = rsqrtf((float)(v1 + 1)); }
    if (b == gridDim.x - 1 && t == 255) offs[N] = E;
    __syncthreads();
    for (int i = t; i < m; i += 256) {
        int p = pb[i];
        int pos = atomicAdd(&cnt[p & 511], 1);
        srcs[bs + pos] = p >> BSHIFT;
    }
}

// ---- W transpose to bf16: WT[j][k] = bf16(W[k][j]) -------------------------
__global__ __launch_bounds__(256) void k_wt(const float* __restrict__ W,
                                            unsigned short* __restrict__ wt) {
    int idx = blockIdx.x * 256 + threadIdx.x;   // 64 blocks -> 16384
    int k = idx >> 7, j = idx & 127;
    float v = W[k * 128 + j];
    wt[j * 128 + k] = f_to_bf_rne(v);
}

// ---- Layer kernels --------------------------------------------------------

// layer0: h'[n][f] = (x0[n] @ W0)[f] * dis[n], stored fp8
__global__ void k_l0(const float* __restrict__ an, const float* __restrict__ pos,
                     const float* __restrict__ W0, const float* __restrict__ dis,
                     unsigned int* __restrict__ h, int N) {
    int idx = blockIdx.x * blockDim.x + threadIdx.x;
    int n = idx >> 5, fq = idx & 31;
    if (n >= N) return;
    float a = an[n];
    float px = pos[n * 3 + 0], py = pos[n * 3 + 1], pz = pos[n * 3 + 2];
    float dn = dis[n];
    const float4 w0 = *(const float4*)&W0[0 * 128 + 4 * fq];
    const float4 w1 = *(const float4*)&W0[1 * 128 + 4 * fq];
    const float4 w2 = *(const float4*)&W0[2 * 128 + 4 * fq];
    const float4 w3 = *(const float4*)&W0[3 * 128 + 4 * fq];
    float4 r;
    r.x = (a * w0.x + px * w1.x + py * w2.x + pz * w3.x) * dn;
    r.y = (a * w0.y + px * w1.y + py * w2.y + pz * w3.y) * dn;
    r.z = (a * w0.z + px * w1.z + py * w2.z + pz * w3.z) * dn;
    r.w = (a * w0.w + px * w1.w + py * w2.w + pz * w3.w) * dn;
    h[(size_t)n * 32 + fq] = f4_to_fp8x4(r.x, r.y, r.z, r.w);
}

// Fused: agg of layer L + transform by W_{L+1} (MFMA) -> h'_{L+1} fp8.
// Phase 1: 64 dst nodes, 8 lanes/node (uint4 = 16B loads), CSR gather-sum,
//          relu(bias + dis*acc) -> bf16 xs tile.
// Phase 2: bf16 MFMA 16x16x32 against staged WT, scale by dis, store fp8.
__global__ __launch_bounds__(256) void k_fused(const unsigned int* __restrict__ x,
        const float* __restrict__ bias, const unsigned short* __restrict__ wt,
        const float* __restrict__ dis, const int* __restrict__ offs,
        const int* __restrict__ srcs, unsigned int* __restrict__ h, int N) {
    __shared__ __align__(16) char ldsb[(64 * XS_STRIDE + 128 * WT_STRIDE) * 2];
    unsigned short* xs  = (unsigned short*)ldsb;          // [64][136] bf16
    unsigned short* wtl = xs + 64 * XS_STRIDE;            // [128][136] bf16
    float* Cs = (float*)ldsb;                             // [64][132] f32 (reuse)

    int t = threadIdx.x;
    int n0 = blockIdx.x * 64;

    // stage WT first so the loads are in flight during the gather phase
    {
        const uint4* wg = (const uint4*)wt;
#pragma unroll
        for (int i = 0; i < 8; i++) {
            int idx = t + i * 256;
            int j = idx >> 4, part = idx & 15;
            uint4 v = wg[idx];
            *(uint4*)&wtl[j * WT_STRIDE + part * 8] = v;
        }
    }

    // gather phase
    {
        const uint4* hp4 = (const uint4*)x;   // row = 8 uint4
        int fq = t & 7, ng = t >> 3;          // 32 nodes per pass
        float bv[16];
        *(float4*)&bv[0]  = *(const float4*)&bias[fq * 16 + 0];
        *(float4*)&bv[4]  = *(const float4*)&bias[fq * 16 + 4];
        *(float4*)&bv[8]  = *(const float4*)&bias[fq * 16 + 8];
        *(float4*)&bv[12] = *(const float4*)&bias[fq * 16 + 12];
#pragma unroll
        for (int half = 0; half < 2; half++) {
            int lrow = half * 32 + ng;
            int n = n0 + lrow;
            float out[16];
            if (n < N) {
                float acc[16], tmp[16];
                fp8x16_to_f(hp4[(size_t)n * 8 + fq], acc);   // self-loop
                int e0 = offs[n], e1 = offs[n + 1];
                int e = e0;
                for (; e + 4 <= e1; e += 4) {
                    int s0 = srcs[e + 0], s1 = srcs[e + 1];
                    int s2 = srcs[e + 2], s3 = srcs[e + 3];
                    uint4 r0 = hp4[(size_t)s0 * 8 + fq];
                    uint4 r1 = hp4[(size_t)s1 * 8 + fq];
                    uint4 r2 = hp4[(size_t)s2 * 8 + fq];
                    uint4 r3 = hp4[(size_t)s3 * 8 + fq];
                    fp8x16_to_f(r0, tmp);
#pragma unroll
                    for (int k = 0; k < 16; k++) acc[k] += tmp[k];
                    fp8x16_to_f(r1, tmp);
#pragma unroll
                    for (int k = 0; k < 16; k++) acc[k] += tmp[k];
                    fp8x16_to_f(r2, tmp);
#pragma unroll
                    for (int k = 0; k < 16; k++) acc[k] += tmp[k];
                    fp8x16_to_f(r3, tmp);
#pragma unroll
                    for (int k = 0; k < 16; k++) acc[k] += tmp[k];
                }
                for (; e < e1; ++e) {
                    int s = srcs[e];
                    fp8x16_to_f(hp4[(size_t)s * 8 + fq], tmp);
#pragma unroll
                    for (int k = 0; k < 16; k++) acc[k] += tmp[k];
                }
                float dn = dis[n];
#pragma unroll
                for (int k = 0; k < 16; k++) out[k] = fmaxf(bv[k] + dn * acc[k], 0.f);
            } else {
#pragma unroll
                for (int k = 0; k < 16; k++) out[k] = 0.f;
            }
            bf16x8 v0, v1;
#pragma unroll
            for (int k = 0; k < 8; k++) {
                v0[k] = (short)f_to_bf_rne(out[k]);
                v1[k] = (short)f_to_bf_rne(out[k + 8]);
            }
            *(bf16x8*)&xs[lrow * XS_STRIDE + fq * 16] = v0;
            *(bf16x8*)&xs[lrow * XS_STRIDE + fq * 16 + 8] = v1;
        }
    }
    __syncthreads();

    // MFMA phase
    int lane = t & 63, wv = t >> 6;
    int m = lane & 15, quad = lane >> 4;
    int rowbase = wv * 16;

    f32x4 acc[8];
#pragma unroll
    for (int c = 0; c < 8; c++) acc[c] = (f32x4){0.f, 0.f, 0.f, 0.f};

#pragma unroll
    for (int kt = 0; kt < 4; kt++) {
        bf16x8 a = *(bf16x8*)&xs[(rowbase + m) * XS_STRIDE + kt * 32 + quad * 8];
#pragma unroll
        for (int c = 0; c < 8; c++) {
            bf16x8 b = *(bf16x8*)&wtl[(c * 16 + m) * WT_STRIDE + kt * 32 + quad * 8];
            acc[c] = __builtin_amdgcn_mfma_f32_16x16x32_bf16(a, b, acc[c], 0, 0, 0);
        }
    }
    __syncthreads();

#pragma unroll
    for (int c = 0; c < 8; c++) {
#pragma unroll
        for (int r = 0; r < 4; r++) {
            Cs[(rowbase + quad * 4 + r) * C_STRIDE + c * 16 + m] = acc[c][r];
        }
    }
    __syncthreads();

    int fq = t & 31, ng = t >> 5;
#pragma unroll
    for (int i = 0; i < 8; i++) {
        int lrow = ng * 8 + i;
        int n = n0 + lrow;
        if (n < N) {
            float4 v = *(const float4*)&Cs[lrow * C_STRIDE + 4 * fq];
            float dn = dis[n];
            h[(size_t)n * 32 + fq] = f4_to_fp8x4(v.x * dn, v.y * dn, v.z * dn, v.w * dn);
        }
    }
}

// Final-layer agg: agg[n] = b + dis[n]*(h'[n] + sum_src h'[src]); fp8 out.
// block = 256 = 32 nodes x 8 lanes; lane handles 16 feats (uint4 = 16B loads)
__global__ __launch_bounds__(256) void k_agg(const unsigned int* __restrict__ h,
                      const float* __restrict__ bias,
                      const float* __restrict__ dis, const int* __restrict__ offs,
                      const int* __restrict__ srcs, unsigned int* __restrict__ agg, int N) {
    int fq = threadIdx.x & 7, ng = threadIdx.x >> 3;
    int n = blockIdx.x * 32 + ng;
    if (n >= N) return;
    const uint4* hp4 = (const uint4*)h;
    float acc[16], tmp[16];
    fp8x16_to_f(hp4[(size_t)n * 8 + fq], acc);
    int e0 = offs[n], e1 = offs[n + 1];
    int e = e0;
    for (; e + 4 <= e1; e += 4) {
        int s0 = srcs[e + 0], s1 = srcs[e + 1], s2 = srcs[e + 2], s3 = srcs[e + 3];
        uint4 r0 = hp4[(size_t)s0 * 8 + fq];
        uint4 r1 = hp4[(size_t)s1 * 8 + fq];
        uint4 r2 = hp4[(size_t)s2 * 8 + fq];
        uint4 r3 = hp4[(size_t)s3 * 8 + fq];
        fp8x16_to_f(r0, tmp);
#pragma unroll
        for (int k = 0; k < 16; k++) acc[k] += tmp[k];
        fp8x16_to_f(r1, tmp);
#pragma unroll
        for (int k = 0; k < 16; k++) acc[k] += tmp[k];
        fp8x16_to_f(r2, tmp);
#pragma unroll
        for (int k = 0; k < 16; k++) acc[k] += tmp[k];
        fp8x16_to_f(r3, tmp);
#pragma unroll
        for (int k = 0; k < 16; k++) acc[k] += tmp[k];
    }
    for (; e < e1; ++e) {
        int s = srcs[e];
        fp8x16_to_f(hp4[(size_t)s * 8 + fq], tmp);
#pragma unroll
        for (int k = 0; k < 16; k++) acc[k] += tmp[k];
    }
    float dn = dis[n];
    float bv[16];
    *(float4*)&bv[0]  = *(const float4*)&bias[fq * 16 + 0];
    *(float4*)&bv[4]  = *(const float4*)&bias[fq * 16 + 4];
    *(float4*)&bv[8]  = *(const float4*)&bias[fq * 16 + 8];
    *(float4*)&bv[12] = *(const float4*)&bias[fq * 16 + 12];
    float o[16];
#pragma unroll
    for (int k = 0; k < 16; k++) o[k] = bv[k] + dn * acc[k];
    uint4 outv;
    outv.x = f4_to_fp8x4(o[0], o[1], o[2], o[3]);
    outv.y = f4_to_fp8x4(o[4], o[5], o[6], o[7]);
    outv.z = f4_to_fp8x4(o[8], o[9], o[10], o[11]);
    outv.w = f4_to_fp8x4(o[12], o[13], o[14], o[15]);
    *(uint4*)&agg[(size_t)n * 32 + fq * 4] = outv;
}

// ---- Pool + head ----------------------------------------------------------

__global__ void k_pool(const unsigned char* __restrict__ x, const int* __restrict__ batch,
                       float* __restrict__ pooled, int N) {
    int g = blockIdx.x >> 3, c = blockIdx.x & 7;
    int start = lower_bound_i(batch, N, g);
    int end   = lower_bound_i(batch, N, g + 1);
    int len = end - start;
    int cb = start + (int)((long)len * c / 8);
    int ce = start + (int)((long)len * (c + 1) / 8);
    int f = threadIdx.x & 127, half = threadIdx.x >> 7;
    float acc = 0.f;
    for (int n = cb + half; n < ce; n += 2) {
        int b = x[(size_t)n * 128 + f];
        vf2 v = __builtin_amdgcn_cvt_pk_f32_fp8(b, false);
        acc += fmaxf(v.x, 0.f);
    }
    __shared__ float sh[128];
    if (half == 1) sh[f] = acc;
    __syncthreads();
    if (half == 0) atomicAdd(&pooled[g * 128 + f], acc + sh[f]);
}

__global__ void k_head(const float* __restrict__ pooled, const int* __restrict__ batch,
                       const float* __restrict__ linW, const float* __restrict__ linb,
                       float* __restrict__ out, int N) {
    int g = threadIdx.x;
    if (g >= 64) return;
    int start = lower_bound_i(batch, N, g);
    int end   = lower_bound_i(batch, N, g + 1);
    float cnt = fmaxf((float)(end - start), 1.0f);
    float logits[8];
#pragma unroll
    for (int j = 0; j < 8; j++) logits[j] = linb[j];
    for (int f = 0; f < 128; f++) {
        float p = pooled[g * 128 + f] / cnt;
#pragma unroll
        for (int j = 0; j < 8; j++) logits[j] += p * linW[f * 8 + j];
    }
    float m = logits[0];
#pragma unroll
    for (int j = 1; j < 8; j++) m = fmaxf(m, logits[j]);
    float s = 0.f;
    float e[8];
#pragma unroll
    for (int j = 0; j < 8; j++) { e[j] = expf(logits[j] - m); s += e[j]; }
#pragma unroll
    for (int j = 0; j < 8; j++) out[g * 8 + j] = e[j] / s;
}

// ---- Launch ---------------------------------------------------------------

extern "C" void kernel_launch(void* const* d_in, const int* in_sizes, int n_in,
                              void* d_out, int out_size, void* d_ws, size_t ws_size,
                              hipStream_t stream) {
    const float* an   = (const float*)d_in[0];
    const float* pos  = (const float*)d_in[1];
    const float* W0   = (const float*)d_in[2];
    const float* b0   = (const float*)d_in[3];
    const float* W1   = (const float*)d_in[4];
    const float* b1   = (const float*)d_in[5];
    const float* W2   = (const float*)d_in[6];
    const float* b2   = (const float*)d_in[7];
    const float* linW = (const float*)d_in[8];
    const float* linb = (const float*)d_in[9];
    const int*   ei   = (const int*)d_in[10];
    const int*   batch= (const int*)d_in[11];

    int N = in_sizes[0];
    int E = in_sizes[10] / 2;
    const int* esrc = ei;
    const int* edst = ei + E;
    int nb = (N + (1 << BSHIFT) - 1) >> BSHIFT;   // 196 for N=100000

    char* p = (char*)d_ws;
    auto carve = [&](size_t bytes) -> void* {
        void* r = (void*)p;
        p += (bytes + 255) & ~(size_t)255;
        return r;
    };
    unsigned int* bufA = (unsigned int*)carve((size_t)N * 128);   // fp8 rows
    unsigned int* bufB = (unsigned int*)carve((size_t)N * 128);
    float* dis    = (float*)carve((size_t)N * 4);
    int*   offs   = (int*)  carve((size_t)(N + 1) * 4);
    int*   srcs   = (int*)  carve((size_t)E * 4);
    int*   pairs  = (int*)  carve((size_t)E * 4);
    int*   gcounts= (int*)  carve((size_t)NB * NBLK * 4);
    int*   bsum   = (int*)  carve(64 * 4);
    unsigned short* wt1 = (unsigned short*)carve(128 * 128 * 2);
    unsigned short* wt2 = (unsigned short*)carve(128 * 128 * 2);
    float* pooled = (float*)carve(64 * 128 * 4);

    hipMemsetAsync(pooled, 0, 64 * 128 * 4, stream);

    // CSR build: deterministic radix partition + hierarchical scan
    k_cnt  <<<NBLK, WG, 0, stream>>>(edst, E, gcounts);
    k_scanA<<<(NB * NBLK) / 1024, WG, 0, stream>>>(gcounts, bsum);
    k_scanB<<<1, 64, 0, stream>>>(bsum);
    k_scat <<<NBLK, WG, 0, stream>>>(esrc, edst, E, gcounts, bsum, pairs);
    k_build<<<nb, WG, 0, stream>>>(pairs, gcounts, bsum, N, E, offs, srcs, dis);

    // W transposes (bf16)
    k_wt<<<64, WG, 0, stream>>>(W1, wt1);
    k_wt<<<64, WG, 0, stream>>>(W2, wt2);

    // layers: l0 -> [agg0 + transform1] -> [agg1 + transform2] -> agg2
    k_l0   <<<((size_t)N * 32 + WG - 1) / WG, WG, 0, stream>>>(an, pos, W0, dis, bufA, N);
    k_fused<<<(N + 63) / 64, WG, 0, stream>>>(bufA, b0, wt1, dis, offs, srcs, bufB, N);
    k_fused<<<(N + 63) / 64, WG, 0, stream>>>(bufB, b1, wt2, dis, offs, srcs, bufA, N);
    k_agg  <<<(N + 31) / 32, WG, 0, stream>>>(bufA, b2, dis, offs, srcs, bufB, N);

    // pool + head
    k_pool<<<64 * 8, WG, 0, stream>>>((const unsigned char*)bufB, batch, pooled, N);
    k_head<<<1, 64, 0, stream>>>(pooled, batch, linW, linb, (float*)d_out, N);
}